// Round 8
// baseline (162.682 us; speedup 1.0000x reference)
//
#include <hip/hip_runtime.h>
#include <stdint.h>

#define D 128

typedef __bf16 bf16x8 __attribute__((ext_vector_type(8)));
typedef float f32x4  __attribute__((ext_vector_type(4)));

__device__ __forceinline__ float b2f(ushort u) {
    uint x = ((uint)u) << 16;
    return __builtin_bit_cast(float, x);
}
__device__ __forceinline__ ushort f2b(float f) {   // round-to-nearest-even
    uint u = __builtin_bit_cast(uint, f);
    u += 0x7FFFu + ((u >> 16) & 1u);
    return (ushort)(u >> 16);
}
// swizzle: XOR low-3 bits of the 16B slot with the 512B pair-row index
__device__ __forceinline__ int swz(int b) { return b ^ (((b >> 9) & 7) << 4); }

// ---------------------------------------------------------------------------
// Weight packing (fragment-major bf16): W1p[((kk*16+nt)*64+lane)*8+t] =
//   W1[kk*32 + 8*(lane>>4) + t][nt*16 + (lane&15)]
// ---------------------------------------------------------------------------
__global__ void pack_w_kernel(const float* __restrict__ W1, const float* __restrict__ W2,
                              ushort* __restrict__ W1p, ushort* __restrict__ W2p) {
    int g = blockIdx.x * blockDim.x + threadIdx.x;
    if (g < 65536) {
        int t = g & 7, l = (g >> 3) & 63, nt = (g >> 9) & 15, kk = g >> 13;
        int krow = kk * 32 + (l >> 4) * 8 + t;
        int col  = nt * 16 + (l & 15);
        W1p[g] = f2b(W1[krow * 256 + col]);
    } else {
        int g2 = g - 65536;
        if (g2 < 32768) {
            int t = g2 & 7, l = (g2 >> 3) & 63, nt = (g2 >> 9) & 7, kk = g2 >> 12;
            int krow = kk * 32 + (l >> 4) * 8 + t;
            int col  = nt * 16 + (l & 15);
            W2p[g2] = f2b(W2[krow * 128 + col]);
        }
    }
}

// ---------------------------------------------------------------------------
// Block-wide inclusive scan (512 threads), u64 payload.
// ---------------------------------------------------------------------------
__device__ __forceinline__ unsigned long long block_scan_u64(unsigned long long v,
                                                             unsigned long long* wsum) {
    int lane = threadIdx.x & 63, wv = threadIdx.x >> 6;
    unsigned long long x = v;
    #pragma unroll
    for (int o = 1; o < 64; o <<= 1) {
        unsigned long long y = __shfl_up(x, (unsigned)o, 64);
        if (lane >= o) x += y;
    }
    if (lane == 63) wsum[wv] = x;
    __syncthreads();
    if (threadIdx.x == 0) {
        unsigned long long acc = 0;
        for (int i = 0; i < 8; ++i) { unsigned long long t = wsum[i]; wsum[i] = acc; acc += t; }
    }
    __syncthreads();
    unsigned long long r = x + wsum[wv];
    __syncthreads();
    return r;
}

// ---------------------------------------------------------------------------
// Plan: pow2-pad items (min 4 rows), counting-sort descending, per-bin tables.
// ---------------------------------------------------------------------------
__global__ void __launch_bounds__(512) plan_kernel(
    const int* __restrict__ limits,
    ushort* __restrict__ sortedIdx, ushort* __restrict__ offRows,
    ushort* __restrict__ binStart, int* __restrict__ nbinsOut)
{
    __shared__ unsigned long long wsum[8];
    __shared__ int cnt[16], base[16];
    __shared__ ushort p2a[512], sIdx[512], binA[512];
    const int tid = threadIdx.x;

    int Lm = limits[tid + 1] - limits[tid];
    Lm = min(max(Lm, 1), 256);
    int p2 = (Lm <= 1) ? 4 : (1 << (32 - __clz(Lm - 1)));
    if (p2 < 4) p2 = 4;
    int cls = 31 - __clz(p2);             // 2..8
    p2a[tid] = (ushort)p2;
    if (tid < 16) cnt[tid] = 0;
    __syncthreads();
    atomicAdd(&cnt[cls], 1);
    __syncthreads();
    if (tid == 0) {
        int b = 0;
        for (int c = 8; c >= 2; --c) { base[c] = b; b += cnt[c]; }
    }
    __syncthreads();

    unsigned long long va = (cls <= 5) ? (1ull << ((cls - 2) * 16)) : 0ull;
    unsigned long long vb = (cls >= 6) ? (1ull << ((cls - 6) * 16)) : 0ull;
    unsigned long long ia = block_scan_u64(va, wsum);
    unsigned long long ib = block_scan_u64(vb, wsum);
    int rank = (cls <= 5) ? (int)((ia >> ((cls - 2) * 16)) & 0xFFFF) - 1
                          : (int)((ib >> ((cls - 6) * 16)) & 0xFFFF) - 1;
    int pos = base[cls] + rank;
    sIdx[pos] = (ushort)tid;
    __syncthreads();

    unsigned long long pv = (unsigned long long)p2a[sIdx[tid]];
    unsigned long long ic = block_scan_u64(pv, wsum);
    unsigned int cumB = (unsigned int)(ic - pv);
    int bin = (int)(cumB >> 8);
    binA[tid] = (ushort)bin;
    sortedIdx[tid] = sIdx[tid];
    offRows[tid]  = (ushort)(cumB & 255);
    __syncthreads();
    if (tid == 0) binStart[0] = 0;
    else if (binA[tid] != binA[tid - 1]) binStart[bin] = (ushort)tid;
    if (tid == 511) { nbinsOut[0] = bin + 1; binStart[bin + 1] = 512; }
}

// ---------------------------------------------------------------------------
// Level body (16 waves, compile-time NMF). GEMM1: N-split-16 (wave w owns H
// cols [16w,16w+16)), all pair fragments. GEMM2: wave = (fragment w>>1,
// nt-half w&1); LN halves combined via LDS partial buffer. 4 barriers.
// ---------------------------------------------------------------------------
template<int NMF>
__device__ __forceinline__ void level_body(
    char* __restrict__ Xw, const char* __restrict__ W2s,
    const unsigned* __restrict__ sk,
    const uint4 (&w1r)[8], const float (&bb1)[4],
    const float (&bb2)[4], const float (&lw)[4], const float (&lb)[4],
    const ushort* __restrict__ cpSk, const ushort* __restrict__ itOff,
    float2* __restrict__ pbuf,
    int G, int tid, int lane, int w)
{
    unsigned pa[NMF];
    #pragma unroll
    for (int mf = 0; mf < NMF; ++mf) pa[mf] = sk[mf * 16 + (lane & 15)];

    // GEMM1 swapped: acc1[mf] = H^T fragment for wave's 16 H-cols
    f32x4 acc1[NMF];
    #pragma unroll
    for (int mf = 0; mf < NMF; ++mf) acc1[mf] = f32x4{0.f, 0.f, 0.f, 0.f};

    constexpr int BATCH = (NMF > 4) ? 4 : NMF;
    #pragma unroll
    for (int kk = 0; kk < 8; ++kk) {
        bf16x8 af = __builtin_bit_cast(bf16x8, w1r[kk]);
        #pragma unroll
        for (int b = 0; b < NMF; b += BATCH) {
            uint4 xv[BATCH];
            #pragma unroll
            for (int u = 0; u < BATCH; ++u) {
                int prow = (int)(pa[b + u] & 0xFFFFu);
                xv[u] = *(const uint4*)(Xw + (prow * 512 + ((kk * 64 + (lane >> 4) * 16) ^ ((prow & 7) << 4))));
            }
            #pragma unroll
            for (int u = 0; u < BATCH; ++u)
                acc1[b + u] = __builtin_amdgcn_mfma_f32_16x16x32_bf16(
                    af, __builtin_bit_cast(bf16x8, xv[u]), acc1[b + u], 0, 0, 0);
        }
    }
    __syncthreads();   // all X reads done

    // H write-back: lane holds 4 consecutive H cols (16w + 4*(lane>>4) + i)
    #pragma unroll
    for (int mf = 0; mf < NMF; ++mf) {
        if ((pa[mf] >> 16) != 0xFFFFu) {
            int prow = (int)(pa[mf] & 0xFFFFu);
            int rbase = prow * 512, sm = (prow & 7) << 4;
            float h0 = fmaxf(acc1[mf][0] + bb1[0], 0.f);
            float h1 = fmaxf(acc1[mf][1] + bb1[1], 0.f);
            float h2 = fmaxf(acc1[mf][2] + bb1[2], 0.f);
            float h3 = fmaxf(acc1[mf][3] + bb1[3], 0.f);
            uint2 pk;
            pk.x = (uint)f2b(h0) | ((uint)f2b(h1) << 16);
            pk.y = (uint)f2b(h2) | ((uint)f2b(h3) << 16);
            *(uint2*)(Xw + (rbase + ((32 * w + 8 * (lane >> 4)) ^ sm))) = pk;
        }
    }
    __syncthreads();   // H visible

    // GEMM2: wave = (fragment f, nt-half h); 4 nt cols each
    const int f = w >> 1, h = w & 1;
    f32x4 acc2[4];
    #pragma unroll
    for (int n = 0; n < 4; ++n) acc2[n] = f32x4{0.f, 0.f, 0.f, 0.f};
    float yv[4][4];
    float s1[4] = {0.f,0.f,0.f,0.f}, s2[4] = {0.f,0.f,0.f,0.f};

    if (f < NMF) {
        int prow = (int)(sk[f * 16 + (lane & 15)] & 0xFFFFu);
        int sm = (prow & 7) << 4, rbase = prow * 512;
        #pragma unroll
        for (int kk = 0; kk < 8; ++kk) {
            uint4 av = *(const uint4*)(Xw + (rbase + ((kk * 64 + (lane >> 4) * 16) ^ sm)));
            bf16x8 afh = __builtin_bit_cast(bf16x8, av);
            #pragma unroll
            for (int n = 0; n < 4; ++n) {
                uint4 bv = *(const uint4*)(W2s + (((kk * 8 + h * 4 + n) * 64 + lane) << 4));
                acc2[n] = __builtin_amdgcn_mfma_f32_16x16x32_bf16(
                    afh, __builtin_bit_cast(bf16x8, bv), acc2[n], 0, 0, 0);
            }
        }
        // partial LN sums over this wave's 64 cols
        #pragma unroll
        for (int n = 0; n < 4; ++n)
            #pragma unroll
            for (int i = 0; i < 4; ++i) {
                float v = acc2[n][i] + bb2[n];
                yv[n][i] = v; s1[i] += v; s2[i] += v * v;
            }
        #pragma unroll
        for (int o = 1; o < 16; o <<= 1)
            #pragma unroll
            for (int i = 0; i < 4; ++i) {
                s1[i] += __shfl_xor(s1[i], o, 64);
                s2[i] += __shfl_xor(s2[i], o, 64);
            }
        if ((lane & 15) == 0) {
            #pragma unroll
            for (int i = 0; i < 4; ++i)
                pbuf[(((f * 16 + (lane >> 4) * 4 + i) << 1) | h)] = float2{s1[i], s2[i]};
        }
    }
    __syncthreads();   // H reads done + partials visible

    if (f < NMF) {
        #pragma unroll
        for (int i = 0; i < 4; ++i) {
            float2 o = pbuf[(((f * 16 + (lane >> 4) * 4 + i) << 1) | (h ^ 1))];
            float S1 = s1[i] + o.x, S2 = s2[i] + o.y;
            float mu = S1 * (1.f / 128.f);
            float var = S2 * (1.f / 128.f) - mu * mu;
            float rs = rsqrtf(var + 1e-5f);
            unsigned se = sk[f * 16 + (lane >> 4) * 4 + i];
            int yd = (int)(se >> 16);
            if (yd != 0xFFFF) {
                #pragma unroll
                for (int n = 0; n < 4; ++n) {
                    int c = (h * 4 + n) * 16 + (lane & 15);
                    float v = (yv[n][i] - mu) * rs * lw[n] + lb[n];
                    *(ushort*)(Xw + swz(yd * 256 + c * 2)) = f2b(v);
                }
            }
        }
    }
    // leftover rows: 1024 threads, one pass (16 chunks per item)
    {
        int it = tid >> 4;
        if (it < G) {
            int srow = (int)cpSk[it];
            if (srow != 0xFFFF) {
                int ch = tid & 15;
                uint4 v = *(const uint4*)(Xw + swz(srow * 256 + ch * 16));
                *(uint4*)(Xw + swz((int)itOff[it] * 256 + ch * 16)) = v;
            }
        }
    }
}

// ---------------------------------------------------------------------------
// Fused tree kernel v6: 1024 threads (16 waves), 1 block/CU, 4 waves/SIMD.
// W1 N-split-16 in regs (32 VGPR), W2 in LDS. Shfl-register binary searches.
// ---------------------------------------------------------------------------
__global__ void __launch_bounds__(1024) tree_kernel(
    const float* __restrict__ args, const int* __restrict__ limits,
    const ushort* __restrict__ W1p, const ushort* __restrict__ W2p,
    const float* __restrict__ b1, const float* __restrict__ b2,
    const float* __restrict__ lnw, const float* __restrict__ lnb,
    const ushort* __restrict__ sortedIdx, const ushort* __restrict__ offRows,
    const ushort* __restrict__ binStart, const int* __restrict__ nbinsP,
    float* __restrict__ out)
{
    __shared__ __align__(16) char Xw[65536];
    __shared__ __align__(16) char W2s[65536];
    __shared__ unsigned int schedAll[1024];     // 8 levels x 128 entries
    __shared__ float2 pbuf[256];                // LN partials [pair][half]
    __shared__ ushort cpSAll[8][64];
    __shared__ ushort itOff[64], itL[64], itOut[64];
    __shared__ int itRow[64];
    __shared__ int nPAll[8];
    __shared__ int gmisc[2];   // 0:G  1:nlev

    const int tid = threadIdx.x, lane = tid & 63, w = tid >> 6;
    const int nbins = *nbinsP;

    // ---- one-time: W1 frag-col w -> regs (wave w owns H cols 16w..16w+15)
    uint4 w1r[8];
    #pragma unroll
    for (int kk = 0; kk < 8; ++kk)
        w1r[kk] = *(const uint4*)(W1p + (size_t)(((kk * 16 + w) * 64 + lane) << 3));

    float bb1[4];
    #pragma unroll
    for (int i = 0; i < 4; ++i)
        bb1[i] = b1[16 * w + 4 * (lane >> 4) + i];
    float bb2[4], lw[4], lb[4];
    #pragma unroll
    for (int n = 0; n < 4; ++n) {
        int c = ((w & 1) * 4 + n) * 16 + (lane & 15);
        bb2[n] = b2[c]; lw[n] = lnw[c]; lb[n] = lnb[c];
    }

    // ---- one-time: W2 packed -> LDS (64KB)
    #pragma unroll
    for (int q = 0; q < 4; ++q) {
        int t = tid + q * 1024;
        *(uint4*)(W2s + t * 16) = *(const uint4*)((const char*)W2p + t * 16);
    }

    for (int bin = blockIdx.x; bin < nbins; bin += gridDim.x) {
        __syncthreads();   // previous bin's LDS readers done
        if (tid == 0) gmisc[0] = (int)binStart[bin + 1] - (int)binStart[bin];
        __syncthreads();
        const int G = gmisc[0];

        if (tid < G) {
            int pos = (int)binStart[bin] + tid;
            int it = sortedIdx[pos];
            itOff[tid] = offRows[pos];
            int a0 = limits[it];
            int Lm = min(max(limits[it + 1] - a0, 1), 256);
            itL[tid] = (ushort)Lm;
            itRow[tid] = a0; itOut[tid] = (ushort)it;
        }
        if (tid < 64) {
            int lev = 0;
            if (tid < G) { int Lm = (int)itL[tid]; lev = (Lm > 1) ? (32 - __clz(Lm - 1)) : 0; }
            #pragma unroll
            for (int o = 32; o; o >>= 1) lev = max(lev, __shfl_xor(lev, o, 64));
            if (tid == 0) gmisc[1] = lev;
        }
        __syncthreads();
        const int nlev = gmisc[1];

        // ---- phase A: wave0 builds all-level schedules (shfl-register
        //      searches); waves 1..15 stage leaves (shfl-register searches)
        if (w == 0) {
            int l   = (lane < G) ? (int)itL[lane] : 0;
            int off = (lane < G) ? (int)itOff[lane] : 0;
            for (int k = 0; k < nlev; ++k) {
                int p = l >> 1;
                int x = p;
                #pragma unroll
                for (int o = 1; o < 64; o <<= 1) { int y = __shfl_up(x, (unsigned)o, 64); if (lane >= o) x += y; }
                int excl = x - p;
                int nPk = __shfl(x, 63, 64);
                if (lane == 0) nPAll[k] = nPk;
                cpSAll[k][lane] = (l > 1 && (l & 1)) ? (ushort)(off + l - 1) : (ushort)0xFFFF;
                int yb = off + (l & 1);
                #pragma unroll
                for (int rep = 0; rep < 2; ++rep) {
                    int e = lane + rep * 64;
                    int lo = 0, hi = G;
                    #pragma unroll
                    for (int s = 0; s < 6; ++s) {       // fixed-trip: all lanes active for shfl
                        int mid = (lo + hi) >> 1;
                        int v = __shfl(excl, mid, 64);
                        if (hi - lo > 1) { if (v <= e) lo = mid; else hi = mid; }
                    }
                    int j = e - __shfl(excl, lo, 64);
                    int offL = __shfl(off, lo, 64);
                    int ybL  = __shfl(yb, lo, 64);
                    unsigned entry = (e < nPk)
                        ? ((unsigned)(((offL >> 1) + j) & 0xFFFF) | ((unsigned)(ybL + j) << 16))
                        : 0xFFFF0000u;
                    schedAll[k * 128 + e] = entry;
                }
                l = p + (l & 1);
            }
        } else {
            // lane-register copies for the row->item search
            int offR = (lane < G) ? (int)itOff[lane] : 0;
            int itLr = (lane < G) ? (int)itL[lane] : 0;
            int rowR = (lane < G) ? itRow[lane] : 0;
            for (int job = tid - 64; job < 4096; job += 960) {
                int r = job >> 4, ch = job & 15;
                int lo = 0, hi = G;
                #pragma unroll
                for (int s = 0; s < 6; ++s) {
                    int mid = (lo + hi) >> 1;
                    int v = __shfl(offR, mid, 64);
                    if (hi - lo > 1) { if (v <= r) lo = mid; else hi = mid; }
                }
                int rel = r - __shfl(offR, lo, 64);
                int Lm  = __shfl(itLr, lo, 64);
                int r0  = __shfl(rowR, lo, 64);
                if (rel >= 0 && rel < Lm) {
                    int src = r0 + rel;
                    const float4 f0 = *(const float4*)(args + (size_t)src * D + ch * 8);
                    const float4 f1 = *(const float4*)(args + (size_t)src * D + ch * 8 + 4);
                    uint4 pk;
                    pk.x = (uint)f2b(f0.x) | ((uint)f2b(f0.y) << 16);
                    pk.y = (uint)f2b(f0.z) | ((uint)f2b(f0.w) << 16);
                    pk.z = (uint)f2b(f1.x) | ((uint)f2b(f1.y) << 16);
                    pk.w = (uint)f2b(f1.z) | ((uint)f2b(f1.w) << 16);
                    *(uint4*)(Xw + swz(r * 256 + ch * 16)) = pk;
                }
            }
        }
        __syncthreads();

        // ---- level loop (NMF-templated straight-line bodies)
        for (int k = 0; k < nlev; ++k) {
            const int nP = nPAll[k];
            if (nP == 0) break;
            const int nMf = (nP + 15) >> 4;
            const unsigned* sk = schedAll + k * 128;
            if (nMf > 4)
                level_body<8>(Xw, W2s, sk, w1r, bb1, bb2, lw, lb, cpSAll[k], itOff, pbuf, G, tid, lane, w);
            else if (nMf > 2)
                level_body<4>(Xw, W2s, sk, w1r, bb1, bb2, lw, lb, cpSAll[k], itOff, pbuf, G, tid, lane, w);
            else if (nMf == 2)
                level_body<2>(Xw, W2s, sk, w1r, bb1, bb2, lw, lb, cpSAll[k], itOff, pbuf, G, tid, lane, w);
            else
                level_body<1>(Xw, W2s, sk, w1r, bb1, bb2, lw, lb, cpSAll[k], itOff, pbuf, G, tid, lane, w);
            __syncthreads();
        }

        // ---- output: root = live row itOff of each item; L==1 exact f32
        for (int j = tid; j < G * 32; j += 1024) {
            int it = j >> 5, grp = j & 31;
            float4 o;
            if ((int)itL[it] == 1) {
                o = *(const float4*)(args + (size_t)itRow[it] * D + grp * 4);
            } else {
                uint2 v = *(const uint2*)(Xw + swz((int)itOff[it] * 256 + grp * 8));
                o.x = b2f((ushort)(v.x & 0xFFFFu));
                o.y = b2f((ushort)(v.x >> 16));
                o.z = b2f((ushort)(v.y & 0xFFFFu));
                o.w = b2f((ushort)(v.y >> 16));
            }
            *(float4*)(out + (size_t)itOut[it] * D + grp * 4) = o;
        }
    }
}

// ---------------------------------------------------------------------------
extern "C" void kernel_launch(void* const* d_in, const int* in_sizes, int n_in,
                              void* d_out, int out_size, void* d_ws, size_t ws_size,
                              hipStream_t stream) {
    const float* args   = (const float*)d_in[0];
    const int*   limits = (const int*)d_in[1];     // harness: integer -> const int*
    const float* W1     = (const float*)d_in[2];
    const float* b1     = (const float*)d_in[3];
    const float* W2     = (const float*)d_in[4];
    const float* b2     = (const float*)d_in[5];
    const float* lnw    = (const float*)d_in[6];
    const float* lnb    = (const float*)d_in[7];

    char* ws = (char*)d_ws;
    ushort* W1p       = (ushort*)(ws);            // 131072 B
    ushort* W2p       = (ushort*)(ws + 131072);   //  65536 B
    ushort* sortedIdx = (ushort*)(ws + 196608);   //   1024 B
    ushort* offRows   = (ushort*)(ws + 197632);   //   1024 B
    ushort* binStart  = (ushort*)(ws + 198656);   //   1040 B
    int*    nbins     = (int*)   (ws + 199744);   //      4 B

    pack_w_kernel<<<384, 256, 0, stream>>>(W1, W2, W1p, W2p);
    plan_kernel<<<1, 512, 0, stream>>>(limits, sortedIdx, offRows, binStart, nbins);
    tree_kernel<<<256, 1024, 0, stream>>>(args, limits, W1p, W2p, b1, b2, lnw, lnb,
                                          sortedIdx, offRows, binStart, nbins, (float*)d_out);
}

// Round 9
// 162.497 us; speedup vs baseline: 1.0011x; 1.0011x over previous
//
#include <hip/hip_runtime.h>
#include <stdint.h>

#define D 128

typedef __bf16 bf16x8 __attribute__((ext_vector_type(8)));
typedef float f32x4  __attribute__((ext_vector_type(4)));

__device__ __forceinline__ float b2f(ushort u) {
    uint x = ((uint)u) << 16;
    return __builtin_bit_cast(float, x);
}
__device__ __forceinline__ ushort f2b(float f) {   // round-to-nearest-even
    uint u = __builtin_bit_cast(uint, f);
    u += 0x7FFFu + ((u >> 16) & 1u);
    return (ushort)(u >> 16);
}
// swizzle: XOR low-3 bits of the 16B slot with the 512B pair-row index
__device__ __forceinline__ int swz(int b) { return b ^ (((b >> 9) & 7) << 4); }

// ---------------------------------------------------------------------------
// Weight packing (fragment-major bf16): W1p[((kk*16+nt)*64+lane)*8+t] =
//   W1[kk*32 + 8*(lane>>4) + t][nt*16 + (lane&15)]
// ---------------------------------------------------------------------------
__global__ void pack_w_kernel(const float* __restrict__ W1, const float* __restrict__ W2,
                              ushort* __restrict__ W1p, ushort* __restrict__ W2p) {
    int g = blockIdx.x * blockDim.x + threadIdx.x;
    if (g < 65536) {
        int t = g & 7, l = (g >> 3) & 63, nt = (g >> 9) & 15, kk = g >> 13;
        int krow = kk * 32 + (l >> 4) * 8 + t;
        int col  = nt * 16 + (l & 15);
        W1p[g] = f2b(W1[krow * 256 + col]);
    } else {
        int g2 = g - 65536;
        if (g2 < 32768) {
            int t = g2 & 7, l = (g2 >> 3) & 63, nt = (g2 >> 9) & 7, kk = g2 >> 12;
            int krow = kk * 32 + (l >> 4) * 8 + t;
            int col  = nt * 16 + (l & 15);
            W2p[g2] = f2b(W2[krow * 128 + col]);
        }
    }
}

// ---------------------------------------------------------------------------
// Block-wide inclusive scan (512 threads), u64 payload.
// ---------------------------------------------------------------------------
__device__ __forceinline__ unsigned long long block_scan_u64(unsigned long long v,
                                                             unsigned long long* wsum) {
    int lane = threadIdx.x & 63, wv = threadIdx.x >> 6;
    unsigned long long x = v;
    #pragma unroll
    for (int o = 1; o < 64; o <<= 1) {
        unsigned long long y = __shfl_up(x, (unsigned)o, 64);
        if (lane >= o) x += y;
    }
    if (lane == 63) wsum[wv] = x;
    __syncthreads();
    if (threadIdx.x == 0) {
        unsigned long long acc = 0;
        for (int i = 0; i < 8; ++i) { unsigned long long t = wsum[i]; wsum[i] = acc; acc += t; }
    }
    __syncthreads();
    unsigned long long r = x + wsum[wv];
    __syncthreads();
    return r;
}

// ---------------------------------------------------------------------------
// Plan: pow2-pad items (min 4 rows), counting-sort descending, per-bin tables.
// ---------------------------------------------------------------------------
__global__ void __launch_bounds__(512) plan_kernel(
    const int* __restrict__ limits,
    ushort* __restrict__ sortedIdx, ushort* __restrict__ offRows,
    ushort* __restrict__ binStart, int* __restrict__ nbinsOut)
{
    __shared__ unsigned long long wsum[8];
    __shared__ int cnt[16], base[16];
    __shared__ ushort p2a[512], sIdx[512], binA[512];
    const int tid = threadIdx.x;

    int Lm = limits[tid + 1] - limits[tid];
    Lm = min(max(Lm, 1), 256);
    int p2 = (Lm <= 1) ? 4 : (1 << (32 - __clz(Lm - 1)));
    if (p2 < 4) p2 = 4;
    int cls = 31 - __clz(p2);             // 2..8
    p2a[tid] = (ushort)p2;
    if (tid < 16) cnt[tid] = 0;
    __syncthreads();
    atomicAdd(&cnt[cls], 1);
    __syncthreads();
    if (tid == 0) {
        int b = 0;
        for (int c = 8; c >= 2; --c) { base[c] = b; b += cnt[c]; }
    }
    __syncthreads();

    unsigned long long va = (cls <= 5) ? (1ull << ((cls - 2) * 16)) : 0ull;
    unsigned long long vb = (cls >= 6) ? (1ull << ((cls - 6) * 16)) : 0ull;
    unsigned long long ia = block_scan_u64(va, wsum);
    unsigned long long ib = block_scan_u64(vb, wsum);
    int rank = (cls <= 5) ? (int)((ia >> ((cls - 2) * 16)) & 0xFFFF) - 1
                          : (int)((ib >> ((cls - 6) * 16)) & 0xFFFF) - 1;
    int pos = base[cls] + rank;
    sIdx[pos] = (ushort)tid;
    __syncthreads();

    unsigned long long pv = (unsigned long long)p2a[sIdx[tid]];
    unsigned long long ic = block_scan_u64(pv, wsum);
    unsigned int cumB = (unsigned int)(ic - pv);
    int bin = (int)(cumB >> 8);
    binA[tid] = (ushort)bin;
    sortedIdx[tid] = sIdx[tid];
    offRows[tid]  = (ushort)(cumB & 255);
    __syncthreads();
    if (tid == 0) binStart[0] = 0;
    else if (binA[tid] != binA[tid - 1]) binStart[bin] = (ushort)tid;
    if (tid == 511) { nbinsOut[0] = bin + 1; binStart[bin + 1] = 512; }
}

// ---------------------------------------------------------------------------
// Level body (16 waves, compile-time NMF). GEMM1: N-split-16 (wave w owns H
// cols [16w,16w+16)), all pair fragments. GEMM2: wave = (fragment w>>1,
// nt-half w&1); LN halves combined via LDS partial buffer. 4 barriers.
// ---------------------------------------------------------------------------
template<int NMF>
__device__ __forceinline__ void level_body(
    char* __restrict__ Xw, const char* __restrict__ W2s,
    const unsigned* __restrict__ sk,
    const uint4 (&w1r)[8], const float (&bb1)[4],
    const float (&bb2)[4], const float (&lw)[4], const float (&lb)[4],
    const ushort* __restrict__ cpSk, const ushort* __restrict__ itOff,
    float2* __restrict__ pbuf,
    int G, int tid, int lane, int w)
{
    unsigned pa[NMF];
    #pragma unroll
    for (int mf = 0; mf < NMF; ++mf) pa[mf] = sk[mf * 16 + (lane & 15)];

    // GEMM1 swapped: acc1[mf] = H^T fragment for wave's 16 H-cols
    f32x4 acc1[NMF];
    #pragma unroll
    for (int mf = 0; mf < NMF; ++mf) acc1[mf] = f32x4{0.f, 0.f, 0.f, 0.f};

    constexpr int BATCH = (NMF > 4) ? 4 : NMF;
    #pragma unroll
    for (int kk = 0; kk < 8; ++kk) {
        bf16x8 af = __builtin_bit_cast(bf16x8, w1r[kk]);
        #pragma unroll
        for (int b = 0; b < NMF; b += BATCH) {
            uint4 xv[BATCH];
            #pragma unroll
            for (int u = 0; u < BATCH; ++u) {
                int prow = (int)(pa[b + u] & 0xFFFFu);
                xv[u] = *(const uint4*)(Xw + (prow * 512 + ((kk * 64 + (lane >> 4) * 16) ^ ((prow & 7) << 4))));
            }
            #pragma unroll
            for (int u = 0; u < BATCH; ++u)
                acc1[b + u] = __builtin_amdgcn_mfma_f32_16x16x32_bf16(
                    af, __builtin_bit_cast(bf16x8, xv[u]), acc1[b + u], 0, 0, 0);
        }
    }
    __syncthreads();   // all X reads done

    // H write-back: lane holds 4 consecutive H cols (16w + 4*(lane>>4) + i)
    #pragma unroll
    for (int mf = 0; mf < NMF; ++mf) {
        if ((pa[mf] >> 16) != 0xFFFFu) {
            int prow = (int)(pa[mf] & 0xFFFFu);
            int rbase = prow * 512, sm = (prow & 7) << 4;
            float h0 = fmaxf(acc1[mf][0] + bb1[0], 0.f);
            float h1 = fmaxf(acc1[mf][1] + bb1[1], 0.f);
            float h2 = fmaxf(acc1[mf][2] + bb1[2], 0.f);
            float h3 = fmaxf(acc1[mf][3] + bb1[3], 0.f);
            uint2 pk;
            pk.x = (uint)f2b(h0) | ((uint)f2b(h1) << 16);
            pk.y = (uint)f2b(h2) | ((uint)f2b(h3) << 16);
            *(uint2*)(Xw + (rbase + ((32 * w + 8 * (lane >> 4)) ^ sm))) = pk;
        }
    }
    __syncthreads();   // H visible

    // GEMM2: wave = (fragment f, nt-half h); 4 nt cols each
    const int f = w >> 1, h = w & 1;
    f32x4 acc2[4];
    #pragma unroll
    for (int n = 0; n < 4; ++n) acc2[n] = f32x4{0.f, 0.f, 0.f, 0.f};
    float yv[4][4];
    float s1[4] = {0.f,0.f,0.f,0.f}, s2[4] = {0.f,0.f,0.f,0.f};

    if (f < NMF) {
        int prow = (int)(sk[f * 16 + (lane & 15)] & 0xFFFFu);
        int sm = (prow & 7) << 4, rbase = prow * 512;
        #pragma unroll
        for (int kk = 0; kk < 8; ++kk) {
            uint4 av = *(const uint4*)(Xw + (rbase + ((kk * 64 + (lane >> 4) * 16) ^ sm)));
            bf16x8 afh = __builtin_bit_cast(bf16x8, av);
            #pragma unroll
            for (int n = 0; n < 4; ++n) {
                uint4 bv = *(const uint4*)(W2s + (((kk * 8 + h * 4 + n) * 64 + lane) << 4));
                acc2[n] = __builtin_amdgcn_mfma_f32_16x16x32_bf16(
                    afh, __builtin_bit_cast(bf16x8, bv), acc2[n], 0, 0, 0);
            }
        }
        // partial LN sums over this wave's 64 cols
        #pragma unroll
        for (int n = 0; n < 4; ++n)
            #pragma unroll
            for (int i = 0; i < 4; ++i) {
                float v = acc2[n][i] + bb2[n];
                yv[n][i] = v; s1[i] += v; s2[i] += v * v;
            }
        #pragma unroll
        for (int o = 1; o < 16; o <<= 1)
            #pragma unroll
            for (int i = 0; i < 4; ++i) {
                s1[i] += __shfl_xor(s1[i], o, 64);
                s2[i] += __shfl_xor(s2[i], o, 64);
            }
        if ((lane & 15) == 0) {
            #pragma unroll
            for (int i = 0; i < 4; ++i)
                pbuf[(((f * 16 + (lane >> 4) * 4 + i) << 1) | h)] = float2{s1[i], s2[i]};
        }
    }
    __syncthreads();   // H reads done + partials visible

    if (f < NMF) {
        #pragma unroll
        for (int i = 0; i < 4; ++i) {
            float2 o = pbuf[(((f * 16 + (lane >> 4) * 4 + i) << 1) | (h ^ 1))];
            float S1 = s1[i] + o.x, S2 = s2[i] + o.y;
            float mu = S1 * (1.f / 128.f);
            float var = S2 * (1.f / 128.f) - mu * mu;
            float rs = rsqrtf(var + 1e-5f);
            unsigned se = sk[f * 16 + (lane >> 4) * 4 + i];
            int yd = (int)(se >> 16);
            if (yd != 0xFFFF) {
                #pragma unroll
                for (int n = 0; n < 4; ++n) {
                    int c = (h * 4 + n) * 16 + (lane & 15);
                    float v = (yv[n][i] - mu) * rs * lw[n] + lb[n];
                    *(ushort*)(Xw + swz(yd * 256 + c * 2)) = f2b(v);
                }
            }
        }
    }
    // leftover rows: 1024 threads, one pass (16 chunks per item)
    {
        int it = tid >> 4;
        if (it < G) {
            int srow = (int)cpSk[it];
            if (srow != 0xFFFF) {
                int ch = tid & 15;
                uint4 v = *(const uint4*)(Xw + swz(srow * 256 + ch * 16));
                *(uint4*)(Xw + swz((int)itOff[it] * 256 + ch * 16)) = v;
            }
        }
    }
}

// ---------------------------------------------------------------------------
// Fused tree kernel v7: 1024 threads (16 waves), __launch_bounds__(1024,4)
// pins 4 waves/EU -> 128-VGPR cap (round 8's 64-VGPR spill fix).
// W1 N-split-16 in regs, W2 in LDS. Shfl-register binary searches.
// ---------------------------------------------------------------------------
__global__ void __launch_bounds__(1024, 4) tree_kernel(
    const float* __restrict__ args, const int* __restrict__ limits,
    const ushort* __restrict__ W1p, const ushort* __restrict__ W2p,
    const float* __restrict__ b1, const float* __restrict__ b2,
    const float* __restrict__ lnw, const float* __restrict__ lnb,
    const ushort* __restrict__ sortedIdx, const ushort* __restrict__ offRows,
    const ushort* __restrict__ binStart, const int* __restrict__ nbinsP,
    float* __restrict__ out)
{
    __shared__ __align__(16) char Xw[65536];
    __shared__ __align__(16) char W2s[65536];
    __shared__ unsigned int schedAll[1024];     // 8 levels x 128 entries
    __shared__ float2 pbuf[256];                // LN partials [pair][half]
    __shared__ ushort cpSAll[8][64];
    __shared__ ushort itOff[64], itL[64], itOut[64];
    __shared__ int itRow[64];
    __shared__ int nPAll[8];
    __shared__ int gmisc[2];   // 0:G  1:nlev

    const int tid = threadIdx.x, lane = tid & 63, w = tid >> 6;
    const int nbins = *nbinsP;

    // ---- one-time: W1 frag-col w -> regs (wave w owns H cols 16w..16w+15)
    uint4 w1r[8];
    #pragma unroll
    for (int kk = 0; kk < 8; ++kk)
        w1r[kk] = *(const uint4*)(W1p + (size_t)(((kk * 16 + w) * 64 + lane) << 3));

    float bb1[4];
    #pragma unroll
    for (int i = 0; i < 4; ++i)
        bb1[i] = b1[16 * w + 4 * (lane >> 4) + i];
    float bb2[4], lw[4], lb[4];
    #pragma unroll
    for (int n = 0; n < 4; ++n) {
        int c = ((w & 1) * 4 + n) * 16 + (lane & 15);
        bb2[n] = b2[c]; lw[n] = lnw[c]; lb[n] = lnb[c];
    }

    // ---- one-time: W2 packed -> LDS (64KB)
    #pragma unroll
    for (int q = 0; q < 4; ++q) {
        int t = tid + q * 1024;
        *(uint4*)(W2s + t * 16) = *(const uint4*)((const char*)W2p + t * 16);
    }

    for (int bin = blockIdx.x; bin < nbins; bin += gridDim.x) {
        __syncthreads();   // previous bin's LDS readers done
        if (tid == 0) gmisc[0] = (int)binStart[bin + 1] - (int)binStart[bin];
        __syncthreads();
        const int G = gmisc[0];

        if (tid < G) {
            int pos = (int)binStart[bin] + tid;
            int it = sortedIdx[pos];
            itOff[tid] = offRows[pos];
            int a0 = limits[it];
            int Lm = min(max(limits[it + 1] - a0, 1), 256);
            itL[tid] = (ushort)Lm;
            itRow[tid] = a0; itOut[tid] = (ushort)it;
        }
        if (tid < 64) {
            int lev = 0;
            if (tid < G) { int Lm = (int)itL[tid]; lev = (Lm > 1) ? (32 - __clz(Lm - 1)) : 0; }
            #pragma unroll
            for (int o = 32; o; o >>= 1) lev = max(lev, __shfl_xor(lev, o, 64));
            if (tid == 0) gmisc[1] = lev;
        }
        __syncthreads();
        const int nlev = gmisc[1];

        // ---- phase A: wave0 builds all-level schedules (shfl-register
        //      searches); waves 1..15 stage leaves (shfl-register searches)
        if (w == 0) {
            int l   = (lane < G) ? (int)itL[lane] : 0;
            int off = (lane < G) ? (int)itOff[lane] : 0;
            for (int k = 0; k < nlev; ++k) {
                int p = l >> 1;
                int x = p;
                #pragma unroll
                for (int o = 1; o < 64; o <<= 1) { int y = __shfl_up(x, (unsigned)o, 64); if (lane >= o) x += y; }
                int excl = x - p;
                int nPk = __shfl(x, 63, 64);
                if (lane == 0) nPAll[k] = nPk;
                cpSAll[k][lane] = (l > 1 && (l & 1)) ? (ushort)(off + l - 1) : (ushort)0xFFFF;
                int yb = off + (l & 1);
                #pragma unroll
                for (int rep = 0; rep < 2; ++rep) {
                    int e = lane + rep * 64;
                    int lo = 0, hi = G;
                    #pragma unroll
                    for (int s = 0; s < 6; ++s) {       // fixed-trip: all lanes active for shfl
                        int mid = (lo + hi) >> 1;
                        int v = __shfl(excl, mid, 64);
                        if (hi - lo > 1) { if (v <= e) lo = mid; else hi = mid; }
                    }
                    int j = e - __shfl(excl, lo, 64);
                    int offL = __shfl(off, lo, 64);
                    int ybL  = __shfl(yb, lo, 64);
                    unsigned entry = (e < nPk)
                        ? ((unsigned)(((offL >> 1) + j) & 0xFFFF) | ((unsigned)(ybL + j) << 16))
                        : 0xFFFF0000u;
                    schedAll[k * 128 + e] = entry;
                }
                l = p + (l & 1);
            }
        } else {
            // lane-register copies for the row->item search
            int offR = (lane < G) ? (int)itOff[lane] : 0;
            int itLr = (lane < G) ? (int)itL[lane] : 0;
            int rowR = (lane < G) ? itRow[lane] : 0;
            for (int job = tid - 64; job < 4096; job += 960) {
                int r = job >> 4, ch = job & 15;
                int lo = 0, hi = G;
                #pragma unroll
                for (int s = 0; s < 6; ++s) {
                    int mid = (lo + hi) >> 1;
                    int v = __shfl(offR, mid, 64);
                    if (hi - lo > 1) { if (v <= r) lo = mid; else hi = mid; }
                }
                int rel = r - __shfl(offR, lo, 64);
                int Lm  = __shfl(itLr, lo, 64);
                int r0  = __shfl(rowR, lo, 64);
                if (rel >= 0 && rel < Lm) {
                    int src = r0 + rel;
                    const float4 f0 = *(const float4*)(args + (size_t)src * D + ch * 8);
                    const float4 f1 = *(const float4*)(args + (size_t)src * D + ch * 8 + 4);
                    uint4 pk;
                    pk.x = (uint)f2b(f0.x) | ((uint)f2b(f0.y) << 16);
                    pk.y = (uint)f2b(f0.z) | ((uint)f2b(f0.w) << 16);
                    pk.z = (uint)f2b(f1.x) | ((uint)f2b(f1.y) << 16);
                    pk.w = (uint)f2b(f1.z) | ((uint)f2b(f1.w) << 16);
                    *(uint4*)(Xw + swz(r * 256 + ch * 16)) = pk;
                }
            }
        }
        __syncthreads();

        // ---- level loop (NMF-templated straight-line bodies)
        for (int k = 0; k < nlev; ++k) {
            const int nP = nPAll[k];
            if (nP == 0) break;
            const int nMf = (nP + 15) >> 4;
            const unsigned* sk = schedAll + k * 128;
            if (nMf > 4)
                level_body<8>(Xw, W2s, sk, w1r, bb1, bb2, lw, lb, cpSAll[k], itOff, pbuf, G, tid, lane, w);
            else if (nMf > 2)
                level_body<4>(Xw, W2s, sk, w1r, bb1, bb2, lw, lb, cpSAll[k], itOff, pbuf, G, tid, lane, w);
            else if (nMf == 2)
                level_body<2>(Xw, W2s, sk, w1r, bb1, bb2, lw, lb, cpSAll[k], itOff, pbuf, G, tid, lane, w);
            else
                level_body<1>(Xw, W2s, sk, w1r, bb1, bb2, lw, lb, cpSAll[k], itOff, pbuf, G, tid, lane, w);
            __syncthreads();
        }

        // ---- output: root = live row itOff of each item; L==1 exact f32
        for (int j = tid; j < G * 32; j += 1024) {
            int it = j >> 5, grp = j & 31;
            float4 o;
            if ((int)itL[it] == 1) {
                o = *(const float4*)(args + (size_t)itRow[it] * D + grp * 4);
            } else {
                uint2 v = *(const uint2*)(Xw + swz((int)itOff[it] * 256 + grp * 8));
                o.x = b2f((ushort)(v.x & 0xFFFFu));
                o.y = b2f((ushort)(v.x >> 16));
                o.z = b2f((ushort)(v.y & 0xFFFFu));
                o.w = b2f((ushort)(v.y >> 16));
            }
            *(float4*)(out + (size_t)itOut[it] * D + grp * 4) = o;
        }
    }
}

// ---------------------------------------------------------------------------
extern "C" void kernel_launch(void* const* d_in, const int* in_sizes, int n_in,
                              void* d_out, int out_size, void* d_ws, size_t ws_size,
                              hipStream_t stream) {
    const float* args   = (const float*)d_in[0];
    const int*   limits = (const int*)d_in[1];     // harness: integer -> const int*
    const float* W1     = (const float*)d_in[2];
    const float* b1     = (const float*)d_in[3];
    const float* W2     = (const float*)d_in[4];
    const float* b2     = (const float*)d_in[5];
    const float* lnw    = (const float*)d_in[6];
    const float* lnb    = (const float*)d_in[7];

    char* ws = (char*)d_ws;
    ushort* W1p       = (ushort*)(ws);            // 131072 B
    ushort* W2p       = (ushort*)(ws + 131072);   //  65536 B
    ushort* sortedIdx = (ushort*)(ws + 196608);   //   1024 B
    ushort* offRows   = (ushort*)(ws + 197632);   //   1024 B
    ushort* binStart  = (ushort*)(ws + 198656);   //   1040 B
    int*    nbins     = (int*)   (ws + 199744);   //      4 B

    pack_w_kernel<<<384, 256, 0, stream>>>(W1, W2, W1p, W2p);
    plan_kernel<<<1, 512, 0, stream>>>(limits, sortedIdx, offRows, binStart, nbins);
    tree_kernel<<<256, 1024, 0, stream>>>(args, limits, W1p, W2p, b1, b2, lnw, lnb,
                                          sortedIdx, offRows, binStart, nbins, (float*)d_out);
}

// Round 10
// 103.855 us; speedup vs baseline: 1.5664x; 1.5647x over previous
//
#include <hip/hip_runtime.h>
#include <stdint.h>

#define D 128

typedef __bf16 bf16x8 __attribute__((ext_vector_type(8)));
typedef float f32x4  __attribute__((ext_vector_type(4)));

__device__ __forceinline__ float b2f(ushort u) {
    uint x = ((uint)u) << 16;
    return __builtin_bit_cast(float, x);
}
__device__ __forceinline__ ushort f2b(float f) {   // round-to-nearest-even
    uint u = __builtin_bit_cast(uint, f);
    u += 0x7FFFu + ((u >> 16) & 1u);
    return (ushort)(u >> 16);
}
// swizzle: XOR low-3 bits of the 16B slot with the 512B pair-row index
__device__ __forceinline__ int swz(int b) { return b ^ (((b >> 9) & 7) << 4); }

// ---------------------------------------------------------------------------
// Weight packing (fragment-major bf16): W1p[((kk*16+nt)*64+lane)*8+t] =
//   W1[kk*32 + 8*(lane>>4) + t][nt*16 + (lane&15)]
// ---------------------------------------------------------------------------
__global__ void pack_w_kernel(const float* __restrict__ W1, const float* __restrict__ W2,
                              ushort* __restrict__ W1p, ushort* __restrict__ W2p) {
    int g = blockIdx.x * blockDim.x + threadIdx.x;
    if (g < 65536) {
        int t = g & 7, l = (g >> 3) & 63, nt = (g >> 9) & 15, kk = g >> 13;
        int krow = kk * 32 + (l >> 4) * 8 + t;
        int col  = nt * 16 + (l & 15);
        W1p[g] = f2b(W1[krow * 256 + col]);
    } else {
        int g2 = g - 65536;
        if (g2 < 32768) {
            int t = g2 & 7, l = (g2 >> 3) & 63, nt = (g2 >> 9) & 7, kk = g2 >> 12;
            int krow = kk * 32 + (l >> 4) * 8 + t;
            int col  = nt * 16 + (l & 15);
            W2p[g2] = f2b(W2[krow * 128 + col]);
        }
    }
}

// ---------------------------------------------------------------------------
// Plan v2: rank items by descending length; chain c = {rank c, rank 511-c}.
// 256 chains, one per block -> near-perfect row balance (~257 rows/chain).
// ---------------------------------------------------------------------------
__global__ void __launch_bounds__(512) plan_kernel(
    const int* __restrict__ limits, int4* __restrict__ chainTab)
{
    __shared__ ushort Ls[512];
    __shared__ ushort rnkIdx[512];
    const int tid = threadIdx.x;
    int Lm = min(max(limits[tid + 1] - limits[tid], 1), 256);
    Ls[tid] = (ushort)Lm;
    __syncthreads();
    int rank = 0;
    for (int j = 0; j < 512; ++j) {
        int Lj = Ls[j];
        rank += (Lj > Lm) || (Lj == Lm && j < tid);
    }
    rnkIdx[rank] = (ushort)tid;
    __syncthreads();
    if (tid < 256) {
        int iA = rnkIdx[tid], iB = rnkIdx[511 - tid];
        int4 t;
        t.x = iA | (((int)Ls[iA]) << 16);
        t.y = iB | (((int)Ls[iB]) << 16);
        t.z = limits[iA];
        t.w = limits[iB];
        chainTab[tid] = t;
    }
}

// ---------------------------------------------------------------------------
// Level body (identical to round 7's proven version). GEMM1 N-split-8 (wave w
// owns H cols [32w,32w+32), W1 in regs), GEMM2 M-split (wave w -> fragment w,
// W2 from LDS), in-register LN. Sentinels pad the fragment tail.
// ---------------------------------------------------------------------------
template<int NMF>
__device__ __forceinline__ void level_body(
    char* __restrict__ Xw, const char* __restrict__ W2s,
    const unsigned* __restrict__ sk,
    const uint4 (&w1r)[8][2], const float (&bb1)[2][4],
    const float (&bb2)[8], const float (&lw)[8], const float (&lb)[8],
    const ushort* __restrict__ cpSk, const ushort* __restrict__ itOff,
    int G, int tid, int lane, int w)
{
    unsigned pa[NMF];
    #pragma unroll
    for (int mf = 0; mf < NMF; ++mf) pa[mf] = sk[mf * 16 + (lane & 15)];

    // GEMM1 swapped: acc1[n][mf] = H^T fragment
    f32x4 acc1[2][NMF];
    #pragma unroll
    for (int n = 0; n < 2; ++n)
        #pragma unroll
        for (int mf = 0; mf < NMF; ++mf) acc1[n][mf] = f32x4{0.f, 0.f, 0.f, 0.f};

    #pragma unroll
    for (int kk = 0; kk < 8; ++kk) {
        uint4 xv[NMF];
        #pragma unroll
        for (int mf = 0; mf < NMF; ++mf) {
            int prow = (int)(pa[mf] & 0xFFFFu);
            xv[mf] = *(const uint4*)(Xw + (prow * 512 + ((kk * 64 + (lane >> 4) * 16) ^ ((prow & 7) << 4))));
        }
        #pragma unroll
        for (int n = 0; n < 2; ++n) {
            bf16x8 af = __builtin_bit_cast(bf16x8, w1r[kk][n]);
            #pragma unroll
            for (int mf = 0; mf < NMF; ++mf)
                acc1[n][mf] = __builtin_amdgcn_mfma_f32_16x16x32_bf16(
                    af, __builtin_bit_cast(bf16x8, xv[mf]), acc1[n][mf], 0, 0, 0);
        }
    }
    __syncthreads();   // all X reads done

    // H write-back: lane holds 4 consecutive H cols of pair row -> b64 writes
    #pragma unroll
    for (int mf = 0; mf < NMF; ++mf) {
        if ((pa[mf] >> 16) != 0xFFFFu) {
            int prow = (int)(pa[mf] & 0xFFFFu);
            int rbase = prow * 512, sm = (prow & 7) << 4;
            #pragma unroll
            for (int n = 0; n < 2; ++n) {
                float h0 = fmaxf(acc1[n][mf][0] + bb1[n][0], 0.f);
                float h1 = fmaxf(acc1[n][mf][1] + bb1[n][1], 0.f);
                float h2 = fmaxf(acc1[n][mf][2] + bb1[n][2], 0.f);
                float h3 = fmaxf(acc1[n][mf][3] + bb1[n][3], 0.f);
                uint2 pk;
                pk.x = (uint)f2b(h0) | ((uint)f2b(h1) << 16);
                pk.y = (uint)f2b(h2) | ((uint)f2b(h3) << 16);
                *(uint2*)(Xw + (rbase + ((64 * w + 32 * n + 8 * (lane >> 4)) ^ sm))) = pk;
            }
        }
    }
    __syncthreads();   // H visible

    // GEMM2: M-split, wave w -> fragment w
    f32x4 acc2[8];
    #pragma unroll
    for (int nt = 0; nt < 8; ++nt) acc2[nt] = f32x4{0.f, 0.f, 0.f, 0.f};

    if (w < NMF) {
        int prow = (int)(sk[w * 16 + (lane & 15)] & 0xFFFFu);
        int sm = (prow & 7) << 4, rbase = prow * 512;
        #pragma unroll
        for (int kk = 0; kk < 8; ++kk) {
            uint4 av = *(const uint4*)(Xw + (rbase + ((kk * 64 + (lane >> 4) * 16) ^ sm)));
            bf16x8 af = __builtin_bit_cast(bf16x8, av);
            #pragma unroll
            for (int nt = 0; nt < 8; ++nt) {
                uint4 bv = *(const uint4*)(W2s + (((kk * 8 + nt) * 64 + lane) << 4));
                acc2[nt] = __builtin_amdgcn_mfma_f32_16x16x32_bf16(
                    af, __builtin_bit_cast(bf16x8, bv), acc2[nt], 0, 0, 0);
            }
        }
    }
    __syncthreads();   // all H reads done

    // LayerNorm + compacted Y write
    if (w < NMF) {
        float yv[8][4];
        float s1[4] = {0.f,0.f,0.f,0.f}, s2[4] = {0.f,0.f,0.f,0.f};
        #pragma unroll
        for (int nt = 0; nt < 8; ++nt)
            #pragma unroll
            for (int i = 0; i < 4; ++i) {
                float v = acc2[nt][i] + bb2[nt];
                yv[nt][i] = v; s1[i] += v; s2[i] += v * v;
            }
        #pragma unroll
        for (int o = 1; o < 16; o <<= 1)
            #pragma unroll
            for (int i = 0; i < 4; ++i) {
                s1[i] += __shfl_xor(s1[i], o, 64);
                s2[i] += __shfl_xor(s2[i], o, 64);
            }
        float mu[4], rs[4];
        #pragma unroll
        for (int i = 0; i < 4; ++i) {
            mu[i] = s1[i] * (1.f / 128.f);
            float var = s2[i] * (1.f / 128.f) - mu[i] * mu[i];
            rs[i] = rsqrtf(var + 1e-5f);
        }
        #pragma unroll
        for (int i = 0; i < 4; ++i) {
            unsigned se = sk[w * 16 + (lane >> 4) * 4 + i];
            int yd = (int)(se >> 16);
            if (yd != 0xFFFF) {
                #pragma unroll
                for (int nt = 0; nt < 8; ++nt) {
                    int c = nt * 16 + (lane & 15);
                    float v = (yv[nt][i] - mu[i]) * rs[i] * lw[nt] + lb[nt];
                    *(ushort*)(Xw + swz(yd * 256 + c * 2)) = f2b(v);
                }
            }
        }
    }
    // leftover rows: copy row (l-1) -> row itOff per odd item
    #pragma unroll
    for (int q = 0; q < 2; ++q) {
        int it = q * 32 + (tid >> 4);
        if (it < G) {
            int srow = (int)cpSk[it];
            if (srow != 0xFFFF) {
                int ch = tid & 15;
                uint4 v = *(const uint4*)(Xw + swz(srow * 256 + ch * 16));
                *(uint4*)(Xw + swz((int)itOff[it] * 256 + ch * 16)) = v;
            }
        }
    }
}

// ---------------------------------------------------------------------------
// Fused tree kernel v9: grid 256 = one chain per block (512 thr, 8 waves).
// Chain = item pair {rank c, rank 511-c}; 1 bin if both fit 256 rows, else 2
// serial bins. G<=2 -> schedules/staging are straight arithmetic (no search).
// W1 in regs, W2 in LDS; level_body identical to round 7 (102 us, verified).
// ---------------------------------------------------------------------------
__global__ void __launch_bounds__(512, 2) tree_kernel(
    const float* __restrict__ args, const int4* __restrict__ chainTab,
    const ushort* __restrict__ W1p, const ushort* __restrict__ W2p,
    const float* __restrict__ b1, const float* __restrict__ b2,
    const float* __restrict__ lnw, const float* __restrict__ lnb,
    float* __restrict__ out)
{
    __shared__ __align__(16) char Xw[65536];
    __shared__ __align__(16) char W2s[65536];
    __shared__ unsigned int schedAll[1024];     // 8 levels x 128 entries
    __shared__ ushort cpSAll[8][2];
    __shared__ ushort itOff[2], itL[2], itOut[2];
    __shared__ int itRow[2];
    __shared__ int nPAll[8];

    const int tid = threadIdx.x, lane = tid & 63, w = tid >> 6;

    // ---- one-time: W1 slice -> regs (wave w owns H cols 32w..32w+31)
    uint4 w1r[8][2];
    #pragma unroll
    for (int kk = 0; kk < 8; ++kk)
        #pragma unroll
        for (int n = 0; n < 2; ++n)
            w1r[kk][n] = *(const uint4*)(W1p + (size_t)(((kk * 16 + (w * 2 + n)) * 64 + lane) << 3));

    float bb1[2][4];
    #pragma unroll
    for (int n = 0; n < 2; ++n)
        #pragma unroll
        for (int i = 0; i < 4; ++i)
            bb1[n][i] = b1[32 * w + 16 * n + 4 * (lane >> 4) + i];
    float bb2[8], lw[8], lb[8];
    #pragma unroll
    for (int nt = 0; nt < 8; ++nt) {
        int c = nt * 16 + (lane & 15);
        bb2[nt] = b2[c]; lw[nt] = lnw[c]; lb[nt] = lnb[c];
    }

    // ---- one-time: W2 packed -> LDS (64KB)
    #pragma unroll
    for (int q = 0; q < 8; ++q) {
        int t = tid + q * 512;
        *(uint4*)(W2s + t * 16) = *(const uint4*)((const char*)W2p + t * 16);
    }

    const int4 ct = chainTab[blockIdx.x];
    const int iA = ct.x & 0xFFFF, La = ct.x >> 16;
    const int iB = ct.y & 0xFFFF, Lb = ct.y >> 16;
    const int a0A = ct.z, a0B = ct.w;
    const int offBfull = (La + 1) & ~1;            // even-aligned B origin
    const bool split = (offBfull + Lb > 256);
    const int npass = split ? 2 : 1;

    for (int pass = 0; pass < npass; ++pass) {
        // bin composition (wave-uniform registers)
        int G, L0, r0, o0, off1 = 0, L1 = 0, r1 = 0, o1 = 0;
        if (!split)          { G = 2; L0 = La; r0 = a0A; o0 = iA; off1 = offBfull; L1 = Lb; r1 = a0B; o1 = iB; }
        else if (pass == 0)  { G = 1; L0 = La; r0 = a0A; o0 = iA; }
        else                 { G = 1; L0 = Lb; r0 = a0B; o0 = iB; }

        __syncthreads();   // previous pass's LDS readers done
        if (tid == 0) {
            itOff[0] = 0;            itL[0] = (ushort)L0; itRow[0] = r0; itOut[0] = (ushort)o0;
            itOff[1] = (ushort)off1; itL[1] = (ushort)L1; itRow[1] = r1; itOut[1] = (ushort)o1;
        }
        int nlev = (L0 > 1) ? (32 - __clz(L0 - 1)) : 0;
        if (G > 1 && L1 > 1) nlev = max(nlev, 32 - __clz(L1 - 1));

        // ---- phase A: wave0 builds all-level schedules (pure arithmetic);
        //      waves 1..7 stage leaves (pure arithmetic item test)
        if (w == 0) {
            int lA_ = L0, lB_ = (G > 1) ? L1 : 0;
            for (int k = 0; k < nlev; ++k) {
                int pA = lA_ >> 1, pB = lB_ >> 1, nPk = pA + pB;
                if (lane == 0) {
                    nPAll[k] = nPk;
                    cpSAll[k][0] = (lA_ > 1 && (lA_ & 1)) ? (ushort)(lA_ - 1) : (ushort)0xFFFF;
                    cpSAll[k][1] = (lB_ > 1 && (lB_ & 1)) ? (ushort)(off1 + lB_ - 1) : (ushort)0xFFFF;
                }
                #pragma unroll
                for (int rep = 0; rep < 2; ++rep) {
                    int e = lane + rep * 64;
                    unsigned entry = 0xFFFF0000u;
                    if (e < pA)
                        entry = (unsigned)e | ((unsigned)((lA_ & 1) + e) << 16);
                    else if (e < nPk) {
                        int j = e - pA;
                        entry = (unsigned)((off1 >> 1) + j) | ((unsigned)(off1 + (lB_ & 1) + j) << 16);
                    }
                    schedAll[k * 128 + e] = entry;
                }
                lA_ = pA + (lA_ & 1);
                lB_ = pB + (lB_ & 1);
            }
        } else {
            for (int job = tid - 64; job < 4096; job += 448) {
                int r = job >> 4, ch = job & 15;
                int src = -1;
                if (r < L0) src = r0 + r;
                else if (G > 1 && r >= off1 && r < off1 + L1) src = r1 + (r - off1);
                if (src >= 0) {
                    const float4 f0 = *(const float4*)(args + (size_t)src * D + ch * 8);
                    const float4 f1 = *(const float4*)(args + (size_t)src * D + ch * 8 + 4);
                    uint4 pk;
                    pk.x = (uint)f2b(f0.x) | ((uint)f2b(f0.y) << 16);
                    pk.y = (uint)f2b(f0.z) | ((uint)f2b(f0.w) << 16);
                    pk.z = (uint)f2b(f1.x) | ((uint)f2b(f1.y) << 16);
                    pk.w = (uint)f2b(f1.z) | ((uint)f2b(f1.w) << 16);
                    *(uint4*)(Xw + swz(r * 256 + ch * 16)) = pk;
                }
            }
        }
        __syncthreads();

        // ---- level loop (NMF-templated straight-line bodies)
        for (int k = 0; k < nlev; ++k) {
            const int nP = nPAll[k];
            if (nP == 0) break;
            const int nMf = (nP + 15) >> 4;
            const unsigned* sk = schedAll + k * 128;
            if (nMf > 4)
                level_body<8>(Xw, W2s, sk, w1r, bb1, bb2, lw, lb, cpSAll[k], itOff, G, tid, lane, w);
            else if (nMf > 2)
                level_body<4>(Xw, W2s, sk, w1r, bb1, bb2, lw, lb, cpSAll[k], itOff, G, tid, lane, w);
            else if (nMf == 2)
                level_body<2>(Xw, W2s, sk, w1r, bb1, bb2, lw, lb, cpSAll[k], itOff, G, tid, lane, w);
            else
                level_body<1>(Xw, W2s, sk, w1r, bb1, bb2, lw, lb, cpSAll[k], itOff, G, tid, lane, w);
            __syncthreads();
        }

        // ---- output: root = live row itOff of each item; L==1 exact f32
        for (int j = tid; j < G * 32; j += 512) {
            int it = j >> 5, grp = j & 31;
            float4 o;
            if ((int)itL[it] == 1) {
                o = *(const float4*)(args + (size_t)itRow[it] * D + grp * 4);
            } else {
                uint2 v = *(const uint2*)(Xw + swz((int)itOff[it] * 256 + grp * 8));
                o.x = b2f((ushort)(v.x & 0xFFFFu));
                o.y = b2f((ushort)(v.x >> 16));
                o.z = b2f((ushort)(v.y & 0xFFFFu));
                o.w = b2f((ushort)(v.y >> 16));
            }
            *(float4*)(out + (size_t)itOut[it] * D + grp * 4) = o;
        }
    }
}

// ---------------------------------------------------------------------------
extern "C" void kernel_launch(void* const* d_in, const int* in_sizes, int n_in,
                              void* d_out, int out_size, void* d_ws, size_t ws_size,
                              hipStream_t stream) {
    const float* args   = (const float*)d_in[0];
    const int*   limits = (const int*)d_in[1];     // harness: integer -> const int*
    const float* W1     = (const float*)d_in[2];
    const float* b1     = (const float*)d_in[3];
    const float* W2     = (const float*)d_in[4];
    const float* b2     = (const float*)d_in[5];
    const float* lnw    = (const float*)d_in[6];
    const float* lnb    = (const float*)d_in[7];

    char* ws = (char*)d_ws;
    ushort* W1p     = (ushort*)(ws);              // 131072 B
    ushort* W2p     = (ushort*)(ws + 131072);     //  65536 B
    int4*   chainTab= (int4*)  (ws + 196608);     //   4096 B

    pack_w_kernel<<<384, 256, 0, stream>>>(W1, W2, W1p, W2p);
    plan_kernel<<<1, 512, 0, stream>>>(limits, chainTab);
    tree_kernel<<<256, 512, 0, stream>>>(args, chainTab, W1p, W2p, b1, b2, lnw, lnb,
                                         (float*)d_out);
}

// Round 11
// 96.456 us; speedup vs baseline: 1.6866x; 1.0767x over previous
//
#include <hip/hip_runtime.h>
#include <stdint.h>

#define D 128

typedef __bf16 bf16x8 __attribute__((ext_vector_type(8)));
typedef float f32x4  __attribute__((ext_vector_type(4)));

__device__ __forceinline__ float b2f(ushort u) {
    uint x = ((uint)u) << 16;
    return __builtin_bit_cast(float, x);
}
__device__ __forceinline__ ushort f2b(float f) {   // round-to-nearest-even
    uint u = __builtin_bit_cast(uint, f);
    u += 0x7FFFu + ((u >> 16) & 1u);
    return (ushort)(u >> 16);
}
// swizzle: XOR low-3 bits of the 16B slot with the 512B pair-row index
__device__ __forceinline__ int swz(int b) { return b ^ (((b >> 9) & 7) << 4); }

// ---------------------------------------------------------------------------
// prep: blocks 0..191 pack weights (fragment-major bf16); block 192 builds
// the rank-paired chain table (round-10 planner, verbatim logic).
// ---------------------------------------------------------------------------
__global__ void __launch_bounds__(512) prep_kernel(
    const float* __restrict__ W1, const float* __restrict__ W2,
    const int* __restrict__ limits,
    ushort* __restrict__ W1p, ushort* __restrict__ W2p,
    int4* __restrict__ chainTab)
{
    if (blockIdx.x < 192) {
        int g = blockIdx.x * 512 + threadIdx.x;
        if (g < 65536) {
            int t = g & 7, l = (g >> 3) & 63, nt = (g >> 9) & 15, kk = g >> 13;
            int krow = kk * 32 + (l >> 4) * 8 + t;
            int col  = nt * 16 + (l & 15);
            W1p[g] = f2b(W1[krow * 256 + col]);
        } else {
            int g2 = g - 65536;
            int t = g2 & 7, l = (g2 >> 3) & 63, nt = (g2 >> 9) & 7, kk = g2 >> 12;
            int krow = kk * 32 + (l >> 4) * 8 + t;
            int col  = nt * 16 + (l & 15);
            W2p[g2] = f2b(W2[krow * 128 + col]);
        }
        return;
    }
    // ---- chain planner: rank by descending L, pair rank c with rank 511-c
    __shared__ ushort Ls[512];
    __shared__ ushort rnkIdx[512];
    const int tid = threadIdx.x;
    int Lm = min(max(limits[tid + 1] - limits[tid], 1), 256);
    Ls[tid] = (ushort)Lm;
    __syncthreads();
    int rank = 0;
    for (int j = 0; j < 512; ++j) {
        int Lj = Ls[j];
        rank += (Lj > Lm) || (Lj == Lm && j < tid);
    }
    rnkIdx[rank] = (ushort)tid;
    __syncthreads();
    if (tid < 256) {
        int iA = rnkIdx[tid], iB = rnkIdx[511 - tid];
        int4 t;
        t.x = iA | (((int)Ls[iA]) << 16);
        t.y = iB | (((int)Ls[iB]) << 16);
        t.z = limits[iA];
        t.w = limits[iB];
        chainTab[tid] = t;
    }
}

// ---------------------------------------------------------------------------
// Level body, compile-time NMF. GEMM1 runs in NMF/2 passes of 2 fragments
// (acc1[2][2]=16 regs -> no spill); pass p's X-reads overlap pass p-1's
// H-writeback (disjoint rows; sentinel row-0 race benign, results discarded).
// GEMM2 M-split (W2s LDS) with in-place bias; LN consts reloaded per level.
// ---------------------------------------------------------------------------
template<int NMF>
__device__ __forceinline__ void level_body(
    char* __restrict__ Xw, const char* __restrict__ W2s,
    const unsigned* __restrict__ sk,
    const uint4 (&w1r)[8][2], const float (&bb1)[2][4],
    const float* __restrict__ b2, const float* __restrict__ lnw,
    const float* __restrict__ lnb,
    const ushort* __restrict__ cpSk, const ushort* __restrict__ itOff,
    int G, int tid, int lane, int w)
{
    constexpr int FPP   = (NMF >= 2) ? 2 : 1;
    constexpr int NPASS = NMF / FPP;

    #pragma unroll
    for (int p = 0; p < NPASS; ++p) {
        unsigned pa[FPP];
        #pragma unroll
        for (int mf = 0; mf < FPP; ++mf) pa[mf] = sk[(p * FPP + mf) * 16 + (lane & 15)];

        f32x4 acc1[2][FPP];
        #pragma unroll
        for (int n = 0; n < 2; ++n)
            #pragma unroll
            for (int mf = 0; mf < FPP; ++mf) acc1[n][mf] = f32x4{0.f, 0.f, 0.f, 0.f};

        #pragma unroll
        for (int kk = 0; kk < 8; ++kk) {
            uint4 xv[FPP];
            #pragma unroll
            for (int mf = 0; mf < FPP; ++mf) {
                int prow = (int)(pa[mf] & 0xFFFFu);
                xv[mf] = *(const uint4*)(Xw + (prow * 512 + ((kk * 64 + (lane >> 4) * 16) ^ ((prow & 7) << 4))));
            }
            #pragma unroll
            for (int n = 0; n < 2; ++n) {
                bf16x8 af = __builtin_bit_cast(bf16x8, w1r[kk][n]);
                #pragma unroll
                for (int mf = 0; mf < FPP; ++mf)
                    acc1[n][mf] = __builtin_amdgcn_mfma_f32_16x16x32_bf16(
                        af, __builtin_bit_cast(bf16x8, xv[mf]), acc1[n][mf], 0, 0, 0);
            }
        }
        __syncthreads();   // all waves' X reads for this pass done

        // H write-back for this pass (lane holds 4 consecutive H cols)
        #pragma unroll
        for (int mf = 0; mf < FPP; ++mf) {
            if ((pa[mf] >> 16) != 0xFFFFu) {
                int prow = (int)(pa[mf] & 0xFFFFu);
                int rbase = prow * 512, sm = (prow & 7) << 4;
                #pragma unroll
                for (int n = 0; n < 2; ++n) {
                    float h0 = fmaxf(acc1[n][mf][0] + bb1[n][0], 0.f);
                    float h1 = fmaxf(acc1[n][mf][1] + bb1[n][1], 0.f);
                    float h2 = fmaxf(acc1[n][mf][2] + bb1[n][2], 0.f);
                    float h3 = fmaxf(acc1[n][mf][3] + bb1[n][3], 0.f);
                    uint2 pk;
                    pk.x = (uint)f2b(h0) | ((uint)f2b(h1) << 16);
                    pk.y = (uint)f2b(h2) | ((uint)f2b(h3) << 16);
                    *(uint2*)(Xw + (rbase + ((64 * w + 32 * n + 8 * (lane >> 4)) ^ sm))) = pk;
                }
            }
        }
    }
    __syncthreads();   // final pass's H visible

    // GEMM2: M-split, wave w -> fragment w
    f32x4 acc2[8];
    #pragma unroll
    for (int nt = 0; nt < 8; ++nt) acc2[nt] = f32x4{0.f, 0.f, 0.f, 0.f};

    if (w < NMF) {
        int prow = (int)(sk[w * 16 + (lane & 15)] & 0xFFFFu);
        int sm = (prow & 7) << 4, rbase = prow * 512;
        #pragma unroll
        for (int kk = 0; kk < 8; ++kk) {
            uint4 av = *(const uint4*)(Xw + (rbase + ((kk * 64 + (lane >> 4) * 16) ^ sm)));
            bf16x8 af = __builtin_bit_cast(bf16x8, av);
            #pragma unroll
            for (int nt = 0; nt < 8; ++nt) {
                uint4 bv = *(const uint4*)(W2s + (((kk * 8 + nt) * 64 + lane) << 4));
                acc2[nt] = __builtin_amdgcn_mfma_f32_16x16x32_bf16(
                    af, __builtin_bit_cast(bf16x8, bv), acc2[nt], 0, 0, 0);
            }
        }
    }
    __syncthreads();   // all H reads done

    // LayerNorm (in-place on acc2, consts reloaded) + compacted Y write
    if (w < NMF) {
        float s1[4] = {0.f,0.f,0.f,0.f}, s2[4] = {0.f,0.f,0.f,0.f};
        #pragma unroll
        for (int nt = 0; nt < 8; ++nt) {
            float bias = b2[nt * 16 + (lane & 15)];
            #pragma unroll
            for (int i = 0; i < 4; ++i) {
                float v = acc2[nt][i] + bias;
                acc2[nt][i] = v; s1[i] += v; s2[i] += v * v;
            }
        }
        #pragma unroll
        for (int o = 1; o < 16; o <<= 1)
            #pragma unroll
            for (int i = 0; i < 4; ++i) {
                s1[i] += __shfl_xor(s1[i], o, 64);
                s2[i] += __shfl_xor(s2[i], o, 64);
            }
        float lwv[8], lbv[8];
        #pragma unroll
        for (int nt = 0; nt < 8; ++nt) {
            int c = nt * 16 + (lane & 15);
            lwv[nt] = lnw[c]; lbv[nt] = lnb[c];
        }
        float mu[4], rs[4];
        #pragma unroll
        for (int i = 0; i < 4; ++i) {
            mu[i] = s1[i] * (1.f / 128.f);
            float var = s2[i] * (1.f / 128.f) - mu[i] * mu[i];
            rs[i] = rsqrtf(var + 1e-5f);
        }
        #pragma unroll
        for (int i = 0; i < 4; ++i) {
            unsigned se = sk[w * 16 + (lane >> 4) * 4 + i];
            int yd = (int)(se >> 16);
            if (yd != 0xFFFF) {
                #pragma unroll
                for (int nt = 0; nt < 8; ++nt) {
                    int c = nt * 16 + (lane & 15);
                    float v = (acc2[nt][i] - mu[i]) * rs[i] * lwv[nt] + lbv[nt];
                    *(ushort*)(Xw + swz(yd * 256 + c * 2)) = f2b(v);
                }
            }
        }
    }
    // leftover rows: copy row (l-1) -> row itOff per odd item
    #pragma unroll
    for (int q = 0; q < 2; ++q) {
        int it = q * 32 + (tid >> 4);
        if (it < G) {
            int srow = (int)cpSk[it];
            if (srow != 0xFFFF) {
                int ch = tid & 15;
                uint4 v = *(const uint4*)(Xw + swz(srow * 256 + ch * 16));
                *(uint4*)(Xw + swz((int)itOff[it] * 256 + ch * 16)) = v;
            }
        }
    }
}

// ---------------------------------------------------------------------------
// Fused tree kernel v10: grid 256 = one rank-paired chain per block (512 thr).
// Multi-pass GEMM1 (no spill), W1 in regs, W2 in LDS, arithmetic schedules.
// ---------------------------------------------------------------------------
__global__ void __launch_bounds__(512, 2) tree_kernel(
    const float* __restrict__ args, const int4* __restrict__ chainTab,
    const ushort* __restrict__ W1p, const ushort* __restrict__ W2p,
    const float* __restrict__ b1, const float* __restrict__ b2,
    const float* __restrict__ lnw, const float* __restrict__ lnb,
    float* __restrict__ out)
{
    __shared__ __align__(16) char Xw[65536];
    __shared__ __align__(16) char W2s[65536];
    __shared__ unsigned int schedAll[1024];     // 8 levels x 128 entries
    __shared__ ushort cpSAll[8][2];
    __shared__ ushort itOff[2], itL[2], itOut[2];
    __shared__ int itRow[2];
    __shared__ int nPAll[8];

    const int tid = threadIdx.x, lane = tid & 63, w = tid >> 6;

    // ---- one-time: W1 slice -> regs (wave w owns H cols 32w..32w+31)
    uint4 w1r[8][2];
    #pragma unroll
    for (int kk = 0; kk < 8; ++kk)
        #pragma unroll
        for (int n = 0; n < 2; ++n)
            w1r[kk][n] = *(const uint4*)(W1p + (size_t)(((kk * 16 + (w * 2 + n)) * 64 + lane) << 3));

    float bb1[2][4];
    #pragma unroll
    for (int n = 0; n < 2; ++n)
        #pragma unroll
        for (int i = 0; i < 4; ++i)
            bb1[n][i] = b1[32 * w + 16 * n + 4 * (lane >> 4) + i];

    // ---- one-time: W2 packed -> LDS (64KB)
    #pragma unroll
    for (int q = 0; q < 8; ++q) {
        int t = tid + q * 512;
        *(uint4*)(W2s + t * 16) = *(const uint4*)((const char*)W2p + t * 16);
    }

    const int4 ct = chainTab[blockIdx.x];
    const int iA = ct.x & 0xFFFF, La = ct.x >> 16;
    const int iB = ct.y & 0xFFFF, Lb = ct.y >> 16;
    const int a0A = ct.z, a0B = ct.w;
    const int offBfull = (La + 1) & ~1;            // even-aligned B origin
    const bool split = (offBfull + Lb > 256);
    const int npass = split ? 2 : 1;

    for (int pass = 0; pass < npass; ++pass) {
        int G, L0, r0, o0, off1 = 0, L1 = 0, r1 = 0, o1 = 0;
        if (!split)          { G = 2; L0 = La; r0 = a0A; o0 = iA; off1 = offBfull; L1 = Lb; r1 = a0B; o1 = iB; }
        else if (pass == 0)  { G = 1; L0 = La; r0 = a0A; o0 = iA; }
        else                 { G = 1; L0 = Lb; r0 = a0B; o0 = iB; }

        __syncthreads();   // previous pass's LDS readers done
        if (tid == 0) {
            itOff[0] = 0;            itL[0] = (ushort)L0; itRow[0] = r0; itOut[0] = (ushort)o0;
            itOff[1] = (ushort)off1; itL[1] = (ushort)L1; itRow[1] = r1; itOut[1] = (ushort)o1;
        }
        int nlev = (L0 > 1) ? (32 - __clz(L0 - 1)) : 0;
        if (G > 1 && L1 > 1) nlev = max(nlev, 32 - __clz(L1 - 1));

        // ---- phase A: wave0 builds all-level schedules (pure arithmetic);
        //      waves 1..7 stage leaves (pure arithmetic item test)
        if (w == 0) {
            int lA_ = L0, lB_ = (G > 1) ? L1 : 0;
            for (int k = 0; k < nlev; ++k) {
                int pA = lA_ >> 1, pB = lB_ >> 1, nPk = pA + pB;
                if (lane == 0) {
                    nPAll[k] = nPk;
                    cpSAll[k][0] = (lA_ > 1 && (lA_ & 1)) ? (ushort)(lA_ - 1) : (ushort)0xFFFF;
                    cpSAll[k][1] = (lB_ > 1 && (lB_ & 1)) ? (ushort)(off1 + lB_ - 1) : (ushort)0xFFFF;
                }
                #pragma unroll
                for (int rep = 0; rep < 2; ++rep) {
                    int e = lane + rep * 64;
                    unsigned entry = 0xFFFF0000u;
                    if (e < pA)
                        entry = (unsigned)e | ((unsigned)((lA_ & 1) + e) << 16);
                    else if (e < nPk) {
                        int j = e - pA;
                        entry = (unsigned)((off1 >> 1) + j) | ((unsigned)(off1 + (lB_ & 1) + j) << 16);
                    }
                    schedAll[k * 128 + e] = entry;
                }
                lA_ = pA + (lA_ & 1);
                lB_ = pB + (lB_ & 1);
            }
        } else {
            for (int job = tid - 64; job < 4096; job += 448) {
                int r = job >> 4, ch = job & 15;
                int src = -1;
                if (r < L0) src = r0 + r;
                else if (G > 1 && r >= off1 && r < off1 + L1) src = r1 + (r - off1);
                if (src >= 0) {
                    const float4 f0 = *(const float4*)(args + (size_t)src * D + ch * 8);
                    const float4 f1 = *(const float4*)(args + (size_t)src * D + ch * 8 + 4);
                    uint4 pk;
                    pk.x = (uint)f2b(f0.x) | ((uint)f2b(f0.y) << 16);
                    pk.y = (uint)f2b(f0.z) | ((uint)f2b(f0.w) << 16);
                    pk.z = (uint)f2b(f1.x) | ((uint)f2b(f1.y) << 16);
                    pk.w = (uint)f2b(f1.z) | ((uint)f2b(f1.w) << 16);
                    *(uint4*)(Xw + swz(r * 256 + ch * 16)) = pk;
                }
            }
        }
        __syncthreads();

        // ---- level loop (NMF-templated, multi-pass GEMM1 bodies)
        for (int k = 0; k < nlev; ++k) {
            const int nP = nPAll[k];
            if (nP == 0) break;
            const int nMf = (nP + 15) >> 4;
            const unsigned* sk = schedAll + k * 128;
            if (nMf > 4)
                level_body<8>(Xw, W2s, sk, w1r, bb1, b2, lnw, lnb, cpSAll[k], itOff, G, tid, lane, w);
            else if (nMf > 2)
                level_body<4>(Xw, W2s, sk, w1r, bb1, b2, lnw, lnb, cpSAll[k], itOff, G, tid, lane, w);
            else if (nMf == 2)
                level_body<2>(Xw, W2s, sk, w1r, bb1, b2, lnw, lnb, cpSAll[k], itOff, G, tid, lane, w);
            else
                level_body<1>(Xw, W2s, sk, w1r, bb1, b2, lnw, lnb, cpSAll[k], itOff, G, tid, lane, w);
            __syncthreads();
        }

        // ---- output: root = live row itOff of each item; L==1 exact f32
        for (int j = tid; j < G * 32; j += 512) {
            int it = j >> 5, grp = j & 31;
            float4 o;
            if ((int)itL[it] == 1) {
                o = *(const float4*)(args + (size_t)itRow[it] * D + grp * 4);
            } else {
                uint2 v = *(const uint2*)(Xw + swz((int)itOff[it] * 256 + grp * 8));
                o.x = b2f((ushort)(v.x & 0xFFFFu));
                o.y = b2f((ushort)(v.x >> 16));
                o.z = b2f((ushort)(v.y & 0xFFFFu));
                o.w = b2f((ushort)(v.y >> 16));
            }
            *(float4*)(out + (size_t)itOut[it] * D + grp * 4) = o;
        }
    }
}

// ---------------------------------------------------------------------------
extern "C" void kernel_launch(void* const* d_in, const int* in_sizes, int n_in,
                              void* d_out, int out_size, void* d_ws, size_t ws_size,
                              hipStream_t stream) {
    const float* args   = (const float*)d_in[0];
    const int*   limits = (const int*)d_in[1];     // harness: integer -> const int*
    const float* W1     = (const float*)d_in[2];
    const float* b1     = (const float*)d_in[3];
    const float* W2     = (const float*)d_in[4];
    const float* b2     = (const float*)d_in[5];
    const float* lnw    = (const float*)d_in[6];
    const float* lnb    = (const float*)d_in[7];

    char* ws = (char*)d_ws;
    ushort* W1p      = (ushort*)(ws);              // 131072 B
    ushort* W2p      = (ushort*)(ws + 131072);     //  65536 B
    int4*   chainTab = (int4*)  (ws + 196608);     //   4096 B

    prep_kernel<<<193, 512, 0, stream>>>(W1, W2, limits, W1p, W2p, chainTab);
    tree_kernel<<<256, 512, 0, stream>>>(args, chainTab, W1p, W2p, b1, b2, lnw, lnb,
                                         (float*)d_out);
}

// Round 12
// 73.087 us; speedup vs baseline: 2.2259x; 1.3197x over previous
//
#include <hip/hip_runtime.h>
#include <stdint.h>

#define D 128

typedef __bf16 bf16x8 __attribute__((ext_vector_type(8)));
typedef float f32x4  __attribute__((ext_vector_type(4)));

__device__ __forceinline__ float b2f(ushort u) {
    uint x = ((uint)u) << 16;
    return __builtin_bit_cast(float, x);
}
__device__ __forceinline__ ushort f2b(float f) {   // round-to-nearest-even
    uint u = __builtin_bit_cast(uint, f);
    u += 0x7FFFu + ((u >> 16) & 1u);
    return (ushort)(u >> 16);
}
// swizzle: XOR low-3 bits of the 16B slot with the 512B pair-row index
__device__ __forceinline__ int swz(int b) { return b ^ (((b >> 9) & 7) << 4); }

// ---------------------------------------------------------------------------
// prep: blocks 0..191 pack weights (fragment-major bf16); block 192 builds
// the rank-paired chain table.
// ---------------------------------------------------------------------------
__global__ void __launch_bounds__(512) prep_kernel(
    const float* __restrict__ W1, const float* __restrict__ W2,
    const int* __restrict__ limits,
    ushort* __restrict__ W1p, ushort* __restrict__ W2p,
    int4* __restrict__ chainTab)
{
    if (blockIdx.x < 192) {
        int g = blockIdx.x * 512 + threadIdx.x;
        if (g < 65536) {
            int t = g & 7, l = (g >> 3) & 63, nt = (g >> 9) & 15, kk = g >> 13;
            int krow = kk * 32 + (l >> 4) * 8 + t;
            int col  = nt * 16 + (l & 15);
            W1p[g] = f2b(W1[krow * 256 + col]);
        } else {
            int g2 = g - 65536;
            int t = g2 & 7, l = (g2 >> 3) & 63, nt = (g2 >> 9) & 7, kk = g2 >> 12;
            int krow = kk * 32 + (l >> 4) * 8 + t;
            int col  = nt * 16 + (l & 15);
            W2p[g2] = f2b(W2[krow * 128 + col]);
        }
        return;
    }
    // ---- chain planner: rank by descending L, pair rank c with rank 511-c
    __shared__ ushort Ls[512];
    __shared__ ushort rnkIdx[512];
    const int tid = threadIdx.x;
    int Lm = min(max(limits[tid + 1] - limits[tid], 1), 256);
    Ls[tid] = (ushort)Lm;
    __syncthreads();
    int rank = 0;
    for (int j = 0; j < 512; ++j) {
        int Lj = Ls[j];
        rank += (Lj > Lm) || (Lj == Lm && j < tid);
    }
    rnkIdx[rank] = (ushort)tid;
    __syncthreads();
    if (tid < 256) {
        int iA = rnkIdx[tid], iB = rnkIdx[511 - tid];
        int4 t;
        t.x = iA | (((int)Ls[iA]) << 16);
        t.y = iB | (((int)Ls[iB]) << 16);
        t.z = limits[iA];
        t.w = limits[iB];
        chainTab[tid] = t;
    }
}

// ---------------------------------------------------------------------------
// Level body, compile-time NMF (<=8 fragments = <=128 pairs per call; bigger
// levels are chunked by the caller). Multi-pass GEMM1 (acc1[2][2], no spill),
// GEMM2 M-split with W2s in LDS, in-register LN. doLeft gates the leftover
// copy (run only on the last chunk of a level).
// ---------------------------------------------------------------------------
template<int NMF>
__device__ __forceinline__ void level_body(
    char* __restrict__ Xw, const char* __restrict__ W2s,
    const unsigned* __restrict__ sk,
    const uint4 (&w1r)[8][2], const float (&bb1)[2][4],
    const float* __restrict__ b2, const float* __restrict__ lnw,
    const float* __restrict__ lnb,
    const ushort* __restrict__ cpSk, const ushort* __restrict__ itOff,
    int G, bool doLeft, int tid, int lane, int w)
{
    constexpr int FPP   = (NMF >= 2) ? 2 : 1;
    constexpr int NPASS = NMF / FPP;

    #pragma unroll
    for (int p = 0; p < NPASS; ++p) {
        unsigned pa[FPP];
        #pragma unroll
        for (int mf = 0; mf < FPP; ++mf) pa[mf] = sk[(p * FPP + mf) * 16 + (lane & 15)];

        f32x4 acc1[2][FPP];
        #pragma unroll
        for (int n = 0; n < 2; ++n)
            #pragma unroll
            for (int mf = 0; mf < FPP; ++mf) acc1[n][mf] = f32x4{0.f, 0.f, 0.f, 0.f};

        #pragma unroll
        for (int kk = 0; kk < 8; ++kk) {
            uint4 xv[FPP];
            #pragma unroll
            for (int mf = 0; mf < FPP; ++mf) {
                int prow = (int)(pa[mf] & 0xFFFFu);
                xv[mf] = *(const uint4*)(Xw + (prow * 512 + ((kk * 64 + (lane >> 4) * 16) ^ ((prow & 7) << 4))));
            }
            #pragma unroll
            for (int n = 0; n < 2; ++n) {
                bf16x8 af = __builtin_bit_cast(bf16x8, w1r[kk][n]);
                #pragma unroll
                for (int mf = 0; mf < FPP; ++mf)
                    acc1[n][mf] = __builtin_amdgcn_mfma_f32_16x16x32_bf16(
                        af, __builtin_bit_cast(bf16x8, xv[mf]), acc1[n][mf], 0, 0, 0);
            }
        }
        __syncthreads();   // all waves' X reads for this pass done

        // H write-back for this pass (lane holds 4 consecutive H cols)
        #pragma unroll
        for (int mf = 0; mf < FPP; ++mf) {
            if ((pa[mf] >> 16) != 0xFFFFu) {
                int prow = (int)(pa[mf] & 0xFFFFu);
                int rbase = prow * 512, sm = (prow & 7) << 4;
                #pragma unroll
                for (int n = 0; n < 2; ++n) {
                    float h0 = fmaxf(acc1[n][mf][0] + bb1[n][0], 0.f);
                    float h1 = fmaxf(acc1[n][mf][1] + bb1[n][1], 0.f);
                    float h2 = fmaxf(acc1[n][mf][2] + bb1[n][2], 0.f);
                    float h3 = fmaxf(acc1[n][mf][3] + bb1[n][3], 0.f);
                    uint2 pk;
                    pk.x = (uint)f2b(h0) | ((uint)f2b(h1) << 16);
                    pk.y = (uint)f2b(h2) | ((uint)f2b(h3) << 16);
                    *(uint2*)(Xw + (rbase + ((64 * w + 32 * n + 8 * (lane >> 4)) ^ sm))) = pk;
                }
            }
        }
    }
    __syncthreads();   // final pass's H visible

    // GEMM2: M-split, wave w -> fragment w
    f32x4 acc2[8];
    #pragma unroll
    for (int nt = 0; nt < 8; ++nt) acc2[nt] = f32x4{0.f, 0.f, 0.f, 0.f};

    if (w < NMF) {
        int prow = (int)(sk[w * 16 + (lane & 15)] & 0xFFFFu);
        int sm = (prow & 7) << 4, rbase = prow * 512;
        #pragma unroll
        for (int kk = 0; kk < 8; ++kk) {
            uint4 av = *(const uint4*)(Xw + (rbase + ((kk * 64 + (lane >> 4) * 16) ^ sm)));
            bf16x8 af = __builtin_bit_cast(bf16x8, av);
            #pragma unroll
            for (int nt = 0; nt < 8; ++nt) {
                uint4 bv = *(const uint4*)(W2s + (((kk * 8 + nt) * 64 + lane) << 4));
                acc2[nt] = __builtin_amdgcn_mfma_f32_16x16x32_bf16(
                    af, __builtin_bit_cast(bf16x8, bv), acc2[nt], 0, 0, 0);
            }
        }
    }
    __syncthreads();   // all H reads done

    // LayerNorm (in-place on acc2) + compacted Y write
    if (w < NMF) {
        float s1[4] = {0.f,0.f,0.f,0.f}, s2[4] = {0.f,0.f,0.f,0.f};
        #pragma unroll
        for (int nt = 0; nt < 8; ++nt) {
            float bias = b2[nt * 16 + (lane & 15)];
            #pragma unroll
            for (int i = 0; i < 4; ++i) {
                float v = acc2[nt][i] + bias;
                acc2[nt][i] = v; s1[i] += v; s2[i] += v * v;
            }
        }
        #pragma unroll
        for (int o = 1; o < 16; o <<= 1)
            #pragma unroll
            for (int i = 0; i < 4; ++i) {
                s1[i] += __shfl_xor(s1[i], o, 64);
                s2[i] += __shfl_xor(s2[i], o, 64);
            }
        float lwv[8], lbv[8];
        #pragma unroll
        for (int nt = 0; nt < 8; ++nt) {
            int c = nt * 16 + (lane & 15);
            lwv[nt] = lnw[c]; lbv[nt] = lnb[c];
        }
        float mu[4], rs[4];
        #pragma unroll
        for (int i = 0; i < 4; ++i) {
            mu[i] = s1[i] * (1.f / 128.f);
            float var = s2[i] * (1.f / 128.f) - mu[i] * mu[i];
            rs[i] = rsqrtf(var + 1e-5f);
        }
        #pragma unroll
        for (int i = 0; i < 4; ++i) {
            unsigned se = sk[w * 16 + (lane >> 4) * 4 + i];
            int yd = (int)(se >> 16);
            if (yd != 0xFFFF) {
                #pragma unroll
                for (int nt = 0; nt < 8; ++nt) {
                    int c = nt * 16 + (lane & 15);
                    float v = (acc2[nt][i] - mu[i]) * rs[i] * lwv[nt] + lbv[nt];
                    *(ushort*)(Xw + swz(yd * 256 + c * 2)) = f2b(v);
                }
            }
        }
    }
    // leftover rows: copy row (l-1) -> row itOff per odd item (last chunk only)
    if (doLeft) {
        #pragma unroll
        for (int q = 0; q < 2; ++q) {
            int it = q * 32 + (tid >> 4);
            if (it < G) {
                int srow = (int)cpSk[it];
                if (srow != 0xFFFF) {
                    int ch = tid & 15;
                    uint4 v = *(const uint4*)(Xw + swz(srow * 256 + ch * 16));
                    *(uint4*)(Xw + swz((int)itOff[it] * 256 + ch * 16)) = v;
                }
            }
        }
    }
}

// ---------------------------------------------------------------------------
// Fused tree kernel v11: Xw grown to 352 element rows (90KB) so nearly every
// rank-paired chain runs in ONE pass (no serial split). Levels with >128
// pairs are processed in 128-pair chunks reusing level_body<=8>. Fallback
// 2-pass split retained for chains > 352 rows.
// ---------------------------------------------------------------------------
__global__ void __launch_bounds__(512, 2) tree_kernel(
    const float* __restrict__ args, const int4* __restrict__ chainTab,
    const ushort* __restrict__ W1p, const ushort* __restrict__ W2p,
    const float* __restrict__ b1, const float* __restrict__ b2,
    const float* __restrict__ lnw, const float* __restrict__ lnb,
    float* __restrict__ out)
{
    __shared__ __align__(16) char Xw[90112];        // 352 element rows x 256B
    __shared__ __align__(16) char W2s[65536];
    __shared__ unsigned int schedAll[1536];         // 8 levels x 192 entries
    __shared__ ushort cpSAll[8][2];
    __shared__ ushort itOff[2], itL[2], itOut[2];
    __shared__ int itRow[2];
    __shared__ int nPAll[8];

    const int tid = threadIdx.x, lane = tid & 63, w = tid >> 6;

    // ---- one-time: W1 slice -> regs (wave w owns H cols 32w..32w+31)
    uint4 w1r[8][2];
    #pragma unroll
    for (int kk = 0; kk < 8; ++kk)
        #pragma unroll
        for (int n = 0; n < 2; ++n)
            w1r[kk][n] = *(const uint4*)(W1p + (size_t)(((kk * 16 + (w * 2 + n)) * 64 + lane) << 3));

    float bb1[2][4];
    #pragma unroll
    for (int n = 0; n < 2; ++n)
        #pragma unroll
        for (int i = 0; i < 4; ++i)
            bb1[n][i] = b1[32 * w + 16 * n + 4 * (lane >> 4) + i];

    // ---- one-time: W2 packed -> LDS (64KB)
    #pragma unroll
    for (int q = 0; q < 8; ++q) {
        int t = tid + q * 512;
        *(uint4*)(W2s + t * 16) = *(const uint4*)((const char*)W2p + t * 16);
    }

    const int4 ct = chainTab[blockIdx.x];
    const int iA = ct.x & 0xFFFF, La = ct.x >> 16;
    const int iB = ct.y & 0xFFFF, Lb = ct.y >> 16;
    const int a0A = ct.z, a0B = ct.w;
    const int offBfull = (La + 1) & ~1;            // even-aligned B origin
    const bool split = (offBfull + Lb > 352);      // Xw capacity (rarely hit)
    const int npass = split ? 2 : 1;

    for (int pass = 0; pass < npass; ++pass) {
        int G, L0, r0, o0, off1 = 0, L1 = 0, r1 = 0, o1 = 0;
        if (!split)          { G = 2; L0 = La; r0 = a0A; o0 = iA; off1 = offBfull; L1 = Lb; r1 = a0B; o1 = iB; }
        else if (pass == 0)  { G = 1; L0 = La; r0 = a0A; o0 = iA; }
        else                 { G = 1; L0 = Lb; r0 = a0B; o0 = iB; }

        __syncthreads();   // previous pass's LDS readers done
        if (tid == 0) {
            itOff[0] = 0;            itL[0] = (ushort)L0; itRow[0] = r0; itOut[0] = (ushort)o0;
            itOff[1] = (ushort)off1; itL[1] = (ushort)L1; itRow[1] = r1; itOut[1] = (ushort)o1;
        }
        int nlev = (L0 > 1) ? (32 - __clz(L0 - 1)) : 0;
        if (G > 1 && L1 > 1) nlev = max(nlev, 32 - __clz(L1 - 1));

        // ---- phase A: wave0 builds all-level schedules (pure arithmetic);
        //      waves 1..7 stage leaves (pure arithmetic item test)
        if (w == 0) {
            int lA_ = L0, lB_ = (G > 1) ? L1 : 0;
            for (int k = 0; k < nlev; ++k) {
                int pA = lA_ >> 1, pB = lB_ >> 1, nPk = pA + pB;
                if (lane == 0) {
                    nPAll[k] = nPk;
                    cpSAll[k][0] = (lA_ > 1 && (lA_ & 1)) ? (ushort)(lA_ - 1) : (ushort)0xFFFF;
                    cpSAll[k][1] = (lB_ > 1 && (lB_ & 1)) ? (ushort)(off1 + lB_ - 1) : (ushort)0xFFFF;
                }
                #pragma unroll
                for (int rep = 0; rep < 3; ++rep) {
                    int e = lane + rep * 64;
                    unsigned entry = 0xFFFF0000u;
                    if (e < pA)
                        entry = (unsigned)e | ((unsigned)((lA_ & 1) + e) << 16);
                    else if (e < nPk) {
                        int j = e - pA;
                        entry = (unsigned)((off1 >> 1) + j) | ((unsigned)(off1 + (lB_ & 1) + j) << 16);
                    }
                    schedAll[k * 192 + e] = entry;
                }
                lA_ = pA + (lA_ & 1);
                lB_ = pB + (lB_ & 1);
            }
        } else {
            for (int job = tid - 64; job < 5632; job += 448) {
                int r = job >> 4, ch = job & 15;
                int src = -1;
                if (r < L0) src = r0 + r;
                else if (G > 1 && r >= off1 && r < off1 + L1) src = r1 + (r - off1);
                if (src >= 0) {
                    const float4 f0 = *(const float4*)(args + (size_t)src * D + ch * 8);
                    const float4 f1 = *(const float4*)(args + (size_t)src * D + ch * 8 + 4);
                    uint4 pk;
                    pk.x = (uint)f2b(f0.x) | ((uint)f2b(f0.y) << 16);
                    pk.y = (uint)f2b(f0.z) | ((uint)f2b(f0.w) << 16);
                    pk.z = (uint)f2b(f1.x) | ((uint)f2b(f1.y) << 16);
                    pk.w = (uint)f2b(f1.z) | ((uint)f2b(f1.w) << 16);
                    *(uint4*)(Xw + swz(r * 256 + ch * 16)) = pk;
                }
            }
        }
        __syncthreads();

        // ---- level loop; levels >128 pairs run in 128-pair chunks
        for (int k = 0; k < nlev; ++k) {
            const int nP = nPAll[k];
            if (nP == 0) break;
            int done = 0;
            while (done < nP) {
                const int chunk = min(nP - done, 128);
                const int nMf = (chunk + 15) >> 4;
                const bool last = (done + chunk >= nP);
                const unsigned* sk = schedAll + k * 192 + done;
                if (nMf > 4)
                    level_body<8>(Xw, W2s, sk, w1r, bb1, b2, lnw, lnb, cpSAll[k], itOff, G, last, tid, lane, w);
                else if (nMf > 2)
                    level_body<4>(Xw, W2s, sk, w1r, bb1, b2, lnw, lnb, cpSAll[k], itOff, G, last, tid, lane, w);
                else if (nMf == 2)
                    level_body<2>(Xw, W2s, sk, w1r, bb1, b2, lnw, lnb, cpSAll[k], itOff, G, last, tid, lane, w);
                else
                    level_body<1>(Xw, W2s, sk, w1r, bb1, b2, lnw, lnb, cpSAll[k], itOff, G, last, tid, lane, w);
                __syncthreads();
                done += chunk;
            }
        }

        // ---- output: root = live row itOff of each item; L==1 exact f32
        for (int j = tid; j < G * 32; j += 512) {
            int it = j >> 5, grp = j & 31;
            float4 o;
            if ((int)itL[it] == 1) {
                o = *(const float4*)(args + (size_t)itRow[it] * D + grp * 4);
            } else {
                uint2 v = *(const uint2*)(Xw + swz((int)itOff[it] * 256 + grp * 8));
                o.x = b2f((ushort)(v.x & 0xFFFFu));
                o.y = b2f((ushort)(v.x >> 16));
                o.z = b2f((ushort)(v.y & 0xFFFFu));
                o.w = b2f((ushort)(v.y >> 16));
            }
            *(float4*)(out + (size_t)itOut[it] * D + grp * 4) = o;
        }
    }
}

// ---------------------------------------------------------------------------
extern "C" void kernel_launch(void* const* d_in, const int* in_sizes, int n_in,
                              void* d_out, int out_size, void* d_ws, size_t ws_size,
                              hipStream_t stream) {
    const float* args   = (const float*)d_in[0];
    const int*   limits = (const int*)d_in[1];     // harness: integer -> const int*
    const float* W1     = (const float*)d_in[2];
    const float* b1     = (const float*)d_in[3];
    const float* W2     = (const float*)d_in[4];
    const float* b2     = (const float*)d_in[5];
    const float* lnw    = (const float*)d_in[6];
    const float* lnb    = (const float*)d_in[7];

    char* ws = (char*)d_ws;
    ushort* W1p      = (ushort*)(ws);              // 131072 B
    ushort* W2p      = (ushort*)(ws + 131072);     //  65536 B
    int4*   chainTab = (int4*)  (ws + 196608);     //   4096 B

    prep_kernel<<<193, 512, 0, stream>>>(W1, W2, limits, W1p, W2p, chainTab);
    tree_kernel<<<256, 512, 0, stream>>>(args, chainTab, W1p, W2p, b1, b2, lnw, lnb,
                                         (float*)d_out);
}

// Round 13
// 64.896 us; speedup vs baseline: 2.5068x; 1.1262x over previous
//
#include <hip/hip_runtime.h>
#include <stdint.h>

#define D 128

typedef __bf16 bf16x8 __attribute__((ext_vector_type(8)));
typedef float f32x4  __attribute__((ext_vector_type(4)));

__device__ __forceinline__ float b2f(ushort u) {
    uint x = ((uint)u) << 16;
    return __builtin_bit_cast(float, x);
}
__device__ __forceinline__ ushort f2b(float f) {   // round-to-nearest-even
    uint u = __builtin_bit_cast(uint, f);
    u += 0x7FFFu + ((u >> 16) & 1u);
    return (ushort)(u >> 16);
}
// swizzle: XOR low-3 bits of the 16B slot with the 512B pair-row index
__device__ __forceinline__ int swz(int b) { return b ^ (((b >> 9) & 7) << 4); }

// ---------------------------------------------------------------------------
// prep: blocks 0..191 pack weights (fragment-major bf16); block 192 builds
// the rank-paired chain table.
// ---------------------------------------------------------------------------
__global__ void __launch_bounds__(512) prep_kernel(
    const float* __restrict__ W1, const float* __restrict__ W2,
    const int* __restrict__ limits,
    ushort* __restrict__ W1p, ushort* __restrict__ W2p,
    int4* __restrict__ chainTab)
{
    if (blockIdx.x < 192) {
        int g = blockIdx.x * 512 + threadIdx.x;
        if (g < 65536) {
            int t = g & 7, l = (g >> 3) & 63, nt = (g >> 9) & 15, kk = g >> 13;
            int krow = kk * 32 + (l >> 4) * 8 + t;
            int col  = nt * 16 + (l & 15);
            W1p[g] = f2b(W1[krow * 256 + col]);
        } else {
            int g2 = g - 65536;
            int t = g2 & 7, l = (g2 >> 3) & 63, nt = (g2 >> 9) & 7, kk = g2 >> 12;
            int krow = kk * 32 + (l >> 4) * 8 + t;
            int col  = nt * 16 + (l & 15);
            W2p[g2] = f2b(W2[krow * 128 + col]);
        }
        return;
    }
    // ---- chain planner: rank by descending L, pair rank c with rank 511-c
    __shared__ ushort Ls[512];
    __shared__ ushort rnkIdx[512];
    const int tid = threadIdx.x;
    int Lm = min(max(limits[tid + 1] - limits[tid], 1), 256);
    Ls[tid] = (ushort)Lm;
    __syncthreads();
    int rank = 0;
    for (int j = 0; j < 512; ++j) {
        int Lj = Ls[j];
        rank += (Lj > Lm) || (Lj == Lm && j < tid);
    }
    rnkIdx[rank] = (ushort)tid;
    __syncthreads();
    if (tid < 256) {
        int iA = rnkIdx[tid], iB = rnkIdx[511 - tid];
        int4 t;
        t.x = iA | (((int)Ls[iA]) << 16);
        t.y = iB | (((int)Ls[iB]) << 16);
        t.z = limits[iA];
        t.w = limits[iB];
        chainTab[tid] = t;
    }
}

// ---------------------------------------------------------------------------
// Level body, compile-time NMF (<=8 fragments = <=128 pairs per call).
// GEMM1: multipass FPP=2, W1 in regs (verified r10-12 code).
// GEMM2: operand-SWAPPED, N-split-8: every wave computes ALL fragments for
// its 16 Y-cols from w2r (registers) -- no W2 LDS traffic, tail parallel 8x.
// LN: 2-shfl 16-col partials -> pbuf[wave][pair] -> combine after barrier.
// ---------------------------------------------------------------------------
template<int NMF>
__device__ __forceinline__ void level_body(
    char* __restrict__ Xw, const unsigned* __restrict__ sk,
    const uint4 (&w1r)[8][2], const uint4 (&w2r)[8],
    const float (&bb1)[2][4], const float (&bb2v)[4],
    const float (&lwv)[4], const float (&lbv)[4],
    float2* __restrict__ pbuf,
    const ushort* __restrict__ cpSk, const ushort* __restrict__ itOff,
    int G, bool doLeft, int tid, int lane, int w)
{
    constexpr int FPP   = (NMF >= 2) ? 2 : 1;
    constexpr int NPASS = NMF / FPP;

    // ---- GEMM1 (swapped, N-split-8), FPP fragments per pass ----
    #pragma unroll
    for (int p = 0; p < NPASS; ++p) {
        unsigned pa[FPP];
        #pragma unroll
        for (int mf = 0; mf < FPP; ++mf) pa[mf] = sk[(p * FPP + mf) * 16 + (lane & 15)];

        f32x4 acc1[2][FPP];
        #pragma unroll
        for (int n = 0; n < 2; ++n)
            #pragma unroll
            for (int mf = 0; mf < FPP; ++mf) acc1[n][mf] = f32x4{0.f, 0.f, 0.f, 0.f};

        #pragma unroll
        for (int kk = 0; kk < 8; ++kk) {
            uint4 xv[FPP];
            #pragma unroll
            for (int mf = 0; mf < FPP; ++mf) {
                int prow = (int)(pa[mf] & 0xFFFFu);
                xv[mf] = *(const uint4*)(Xw + (prow * 512 + ((kk * 64 + (lane >> 4) * 16) ^ ((prow & 7) << 4))));
            }
            #pragma unroll
            for (int n = 0; n < 2; ++n) {
                bf16x8 af = __builtin_bit_cast(bf16x8, w1r[kk][n]);
                #pragma unroll
                for (int mf = 0; mf < FPP; ++mf)
                    acc1[n][mf] = __builtin_amdgcn_mfma_f32_16x16x32_bf16(
                        af, __builtin_bit_cast(bf16x8, xv[mf]), acc1[n][mf], 0, 0, 0);
            }
        }
        __syncthreads();   // all waves' X reads for this pass done

        // H write-back for this pass (lane holds 4 consecutive H cols)
        #pragma unroll
        for (int mf = 0; mf < FPP; ++mf) {
            if ((pa[mf] >> 16) != 0xFFFFu) {
                int prow = (int)(pa[mf] & 0xFFFFu);
                int rbase = prow * 512, sm = (prow & 7) << 4;
                #pragma unroll
                for (int n = 0; n < 2; ++n) {
                    float h0 = fmaxf(acc1[n][mf][0] + bb1[n][0], 0.f);
                    float h1 = fmaxf(acc1[n][mf][1] + bb1[n][1], 0.f);
                    float h2 = fmaxf(acc1[n][mf][2] + bb1[n][2], 0.f);
                    float h3 = fmaxf(acc1[n][mf][3] + bb1[n][3], 0.f);
                    uint2 pk;
                    pk.x = (uint)f2b(h0) | ((uint)f2b(h1) << 16);
                    pk.y = (uint)f2b(h2) | ((uint)f2b(h3) << 16);
                    *(uint2*)(Xw + (rbase + ((64 * w + 32 * n + 8 * (lane >> 4)) ^ sm))) = pk;
                }
            }
        }
    }
    __syncthreads();   // final pass's H visible

    // ---- GEMM2 swapped: acc2[mf] = Y^T fragment for wave's 16 Y-cols ----
    unsigned pa2[NMF];
    #pragma unroll
    for (int mf = 0; mf < NMF; ++mf) pa2[mf] = sk[mf * 16 + (lane & 15)];

    f32x4 acc2[NMF];
    #pragma unroll
    for (int mf = 0; mf < NMF; ++mf) acc2[mf] = f32x4{0.f, 0.f, 0.f, 0.f};

    #pragma unroll
    for (int kk = 0; kk < 8; ++kk) {
        bf16x8 af = __builtin_bit_cast(bf16x8, w2r[kk]);
        #pragma unroll
        for (int mf = 0; mf < NMF; ++mf) {
            int prow = (int)(pa2[mf] & 0xFFFFu);
            uint4 hv = *(const uint4*)(Xw + (prow * 512 + ((kk * 64 + (lane >> 4) * 16) ^ ((prow & 7) << 4))));
            acc2[mf] = __builtin_amdgcn_mfma_f32_16x16x32_bf16(
                af, __builtin_bit_cast(bf16x8, hv), acc2[mf], 0, 0, 0);
        }
    }

    // bias + 16-col LN partials -> pbuf[w][pair]
    #pragma unroll
    for (int mf = 0; mf < NMF; ++mf) {
        float s1 = 0.f, s2 = 0.f;
        #pragma unroll
        for (int i = 0; i < 4; ++i) {
            float v = acc2[mf][i] + bb2v[i];
            acc2[mf][i] = v; s1 += v; s2 += v * v;
        }
        s1 += __shfl_xor(s1, 16, 64); s2 += __shfl_xor(s2, 16, 64);
        s1 += __shfl_xor(s1, 32, 64); s2 += __shfl_xor(s2, 32, 64);
        if ((lane >> 4) == 0)
            pbuf[w * 128 + mf * 16 + (lane & 15)] = float2{s1, s2};
    }
    __syncthreads();   // H reads done + partials visible

    // combine partials, normalize, write Y (4 consecutive cols per lane)
    #pragma unroll
    for (int mf = 0; mf < NMF; ++mf) {
        int yd = (int)(pa2[mf] >> 16);
        if (yd != 0xFFFF) {
            int p = mf * 16 + (lane & 15);
            float S1 = 0.f, S2 = 0.f;
            #pragma unroll
            for (int ww = 0; ww < 8; ++ww) {
                float2 o = pbuf[ww * 128 + p];
                S1 += o.x; S2 += o.y;
            }
            float mu = S1 * (1.f / 128.f);
            float var = S2 * (1.f / 128.f) - mu * mu;
            float rs = rsqrtf(var + 1e-5f);
            float v0 = (acc2[mf][0] - mu) * rs * lwv[0] + lbv[0];
            float v1 = (acc2[mf][1] - mu) * rs * lwv[1] + lbv[1];
            float v2 = (acc2[mf][2] - mu) * rs * lwv[2] + lbv[2];
            float v3 = (acc2[mf][3] - mu) * rs * lwv[3] + lbv[3];
            uint2 pk;
            pk.x = (uint)f2b(v0) | ((uint)f2b(v1) << 16);
            pk.y = (uint)f2b(v2) | ((uint)f2b(v3) << 16);
            *(uint2*)(Xw + swz(yd * 256 + (16 * w + 4 * (lane >> 4)) * 2)) = pk;
        }
    }
    // leftover rows: copy row (l-1) -> row itOff per odd item (last chunk only)
    if (doLeft) {
        #pragma unroll
        for (int q = 0; q < 2; ++q) {
            int it = q * 32 + (tid >> 4);
            if (it < G) {
                int srow = (int)cpSk[it];
                if (srow != 0xFFFF) {
                    int ch = tid & 15;
                    uint4 v = *(const uint4*)(Xw + swz(srow * 256 + ch * 16));
                    *(uint4*)(Xw + swz((int)itOff[it] * 256 + ch * 16)) = v;
                }
            }
        }
    }
}

// ---------------------------------------------------------------------------
// Fused tree kernel v12: amdgpu_waves_per_eu(2,2) unlocks the 256-VGPR budget
// (LDS already caps us at 1 block/CU); W1 AND W2 resident in registers;
// GEMM2 swapped N-split-8 (no W2 LDS buffer, tail parallel); 4 barriers/level.
// ---------------------------------------------------------------------------
__global__ void __launch_bounds__(512)
__attribute__((amdgpu_waves_per_eu(2, 2)))
tree_kernel(
    const float* __restrict__ args, const int4* __restrict__ chainTab,
    const ushort* __restrict__ W1p, const ushort* __restrict__ W2p,
    const float* __restrict__ b1, const float* __restrict__ b2,
    const float* __restrict__ lnw, const float* __restrict__ lnb,
    float* __restrict__ out)
{
    __shared__ __align__(16) char Xw[90112];        // 352 element rows x 256B
    __shared__ unsigned int schedAll[1536];         // 8 levels x 192 entries
    __shared__ float2 pbuf[1024];                   // LN partials [wave][pair]
    __shared__ ushort cpSAll[8][2];
    __shared__ ushort itOff[2], itL[2], itOut[2];
    __shared__ int itRow[2];
    __shared__ int nPAll[8];

    const int tid = threadIdx.x, lane = tid & 63, w = tid >> 6;

    // ---- one-time: W1 slice -> regs (wave w owns H cols 32w..32w+31)
    uint4 w1r[8][2];
    #pragma unroll
    for (int kk = 0; kk < 8; ++kk)
        #pragma unroll
        for (int n = 0; n < 2; ++n)
            w1r[kk][n] = *(const uint4*)(W1p + (size_t)(((kk * 16 + (w * 2 + n)) * 64 + lane) << 3));

    // ---- one-time: W2 slice -> regs (wave w owns Y cols 16w..16w+15)
    uint4 w2r[8];
    #pragma unroll
    for (int kk = 0; kk < 8; ++kk)
        w2r[kk] = *(const uint4*)(W2p + (size_t)(((kk * 8 + w) * 64 + lane) << 3));

    float bb1[2][4];
    #pragma unroll
    for (int n = 0; n < 2; ++n)
        #pragma unroll
        for (int i = 0; i < 4; ++i)
            bb1[n][i] = b1[32 * w + 16 * n + 4 * (lane >> 4) + i];
    float bb2v[4], lwv[4], lbv[4];
    #pragma unroll
    for (int i = 0; i < 4; ++i) {
        int c = 16 * w + 4 * (lane >> 4) + i;
        bb2v[i] = b2[c]; lwv[i] = lnw[c]; lbv[i] = lnb[c];
    }

    const int4 ct = chainTab[blockIdx.x];
    const int iA = ct.x & 0xFFFF, La = ct.x >> 16;
    const int iB = ct.y & 0xFFFF, Lb = ct.y >> 16;
    const int a0A = ct.z, a0B = ct.w;
    const int offBfull = (La + 1) & ~1;            // even-aligned B origin
    const bool split = (offBfull + Lb > 352);      // Xw capacity (rarely hit)
    const int npass = split ? 2 : 1;

    for (int pass = 0; pass < npass; ++pass) {
        int G, L0, r0, o0, off1 = 0, L1 = 0, r1 = 0, o1 = 0;
        if (!split)          { G = 2; L0 = La; r0 = a0A; o0 = iA; off1 = offBfull; L1 = Lb; r1 = a0B; o1 = iB; }
        else if (pass == 0)  { G = 1; L0 = La; r0 = a0A; o0 = iA; }
        else                 { G = 1; L0 = Lb; r0 = a0B; o0 = iB; }

        __syncthreads();   // previous pass's LDS readers done
        if (tid == 0) {
            itOff[0] = 0;            itL[0] = (ushort)L0; itRow[0] = r0; itOut[0] = (ushort)o0;
            itOff[1] = (ushort)off1; itL[1] = (ushort)L1; itRow[1] = r1; itOut[1] = (ushort)o1;
        }
        int nlev = (L0 > 1) ? (32 - __clz(L0 - 1)) : 0;
        if (G > 1 && L1 > 1) nlev = max(nlev, 32 - __clz(L1 - 1));

        // ---- phase A: wave0 builds all-level schedules (pure arithmetic);
        //      waves 1..7 stage leaves (pure arithmetic item test)
        if (w == 0) {
            int lA_ = L0, lB_ = (G > 1) ? L1 : 0;
            for (int k = 0; k < nlev; ++k) {
                int pA = lA_ >> 1, pB = lB_ >> 1, nPk = pA + pB;
                if (lane == 0) {
                    nPAll[k] = nPk;
                    cpSAll[k][0] = (lA_ > 1 && (lA_ & 1)) ? (ushort)(lA_ - 1) : (ushort)0xFFFF;
                    cpSAll[k][1] = (lB_ > 1 && (lB_ & 1)) ? (ushort)(off1 + lB_ - 1) : (ushort)0xFFFF;
                }
                #pragma unroll
                for (int rep = 0; rep < 3; ++rep) {
                    int e = lane + rep * 64;
                    unsigned entry = 0xFFFF0000u;
                    if (e < pA)
                        entry = (unsigned)e | ((unsigned)((lA_ & 1) + e) << 16);
                    else if (e < nPk) {
                        int j = e - pA;
                        entry = (unsigned)((off1 >> 1) + j) | ((unsigned)(off1 + (lB_ & 1) + j) << 16);
                    }
                    schedAll[k * 192 + e] = entry;
                }
                lA_ = pA + (lA_ & 1);
                lB_ = pB + (lB_ & 1);
            }
        } else {
            for (int job = tid - 64; job < 5632; job += 448) {
                int r = job >> 4, ch = job & 15;
                int src = -1;
                if (r < L0) src = r0 + r;
                else if (G > 1 && r >= off1 && r < off1 + L1) src = r1 + (r - off1);
                if (src >= 0) {
                    const float4 f0 = *(const float4*)(args + (size_t)src * D + ch * 8);
                    const float4 f1 = *(const float4*)(args + (size_t)src * D + ch * 8 + 4);
                    uint4 pk;
                    pk.x = (uint)f2b(f0.x) | ((uint)f2b(f0.y) << 16);
                    pk.y = (uint)f2b(f0.z) | ((uint)f2b(f0.w) << 16);
                    pk.z = (uint)f2b(f1.x) | ((uint)f2b(f1.y) << 16);
                    pk.w = (uint)f2b(f1.z) | ((uint)f2b(f1.w) << 16);
                    *(uint4*)(Xw + swz(r * 256 + ch * 16)) = pk;
                }
            }
        }
        __syncthreads();

        // ---- level loop; levels >128 pairs run in 128-pair chunks
        for (int k = 0; k < nlev; ++k) {
            const int nP = nPAll[k];
            if (nP == 0) break;
            int done = 0;
            while (done < nP) {
                const int chunk = min(nP - done, 128);
                const int nMf = (chunk + 15) >> 4;
                const bool last = (done + chunk >= nP);
                const unsigned* sk = schedAll + k * 192 + done;
                if (nMf > 4)
                    level_body<8>(Xw, sk, w1r, w2r, bb1, bb2v, lwv, lbv, pbuf, cpSAll[k], itOff, G, last, tid, lane, w);
                else if (nMf > 2)
                    level_body<4>(Xw, sk, w1r, w2r, bb1, bb2v, lwv, lbv, pbuf, cpSAll[k], itOff, G, last, tid, lane, w);
                else if (nMf == 2)
                    level_body<2>(Xw, sk, w1r, w2r, bb1, bb2v, lwv, lbv, pbuf, cpSAll[k], itOff, G, last, tid, lane, w);
                else
                    level_body<1>(Xw, sk, w1r, w2r, bb1, bb2v, lwv, lbv, pbuf, cpSAll[k], itOff, G, last, tid, lane, w);
                __syncthreads();
                done += chunk;
            }
        }

        // ---- output: root = live row itOff of each item; L==1 exact f32
        for (int j = tid; j < G * 32; j += 512) {
            int it = j >> 5, grp = j & 31;
            float4 o;
            if ((int)itL[it] == 1) {
                o = *(const float4*)(args + (size_t)itRow[it] * D + grp * 4);
            } else {
                uint2 v = *(const uint2*)(Xw + swz((int)itOff[it] * 256 + grp * 8));
                o.x = b2f((ushort)(v.x & 0xFFFFu));
                o.y = b2f((ushort)(v.x >> 16));
                o.z = b2f((ushort)(v.y & 0xFFFFu));
                o.w = b2f((ushort)(v.y >> 16));
            }
            *(float4*)(out + (size_t)itOut[it] * D + grp * 4) = o;
        }
    }
}

// ---------------------------------------------------------------------------
extern "C" void kernel_launch(void* const* d_in, const int* in_sizes, int n_in,
                              void* d_out, int out_size, void* d_ws, size_t ws_size,
                              hipStream_t stream) {
    const float* args   = (const float*)d_in[0];
    const int*   limits = (const int*)d_in[1];     // harness: integer -> const int*
    const float* W1     = (const float*)d_in[2];
    const float* b1     = (const float*)d_in[3];
    const float* W2     = (const float*)d_in[4];
    const float* b2     = (const float*)d_in[5];
    const float* lnw    = (const float*)d_in[6];
    const float* lnb    = (const float*)d_in[7];

    char* ws = (char*)d_ws;
    ushort* W1p      = (ushort*)(ws);              // 131072 B
    ushort* W2p      = (ushort*)(ws + 131072);     //  65536 B
    int4*   chainTab = (int4*)  (ws + 196608);     //   4096 B

    prep_kernel<<<193, 512, 0, stream>>>(W1, W2, limits, W1p, W2p, chainTab);
    tree_kernel<<<256, 512, 0, stream>>>(args, chainTab, W1p, W2p, b1, b2, lnw, lnb,
                                         (float*)d_out);
}